// Round 5
// baseline (838.184 us; speedup 1.0000x reference)
//
#include <hip/hip_runtime.h>
#include <math.h>

typedef short short8 __attribute__((ext_vector_type(8)));
typedef float f32x16 __attribute__((ext_vector_type(16)));

__device__ __forceinline__ unsigned short f2bf(float f) {
  unsigned u = __float_as_uint(f);
  unsigned r = u + 0x7fffu + ((u >> 16) & 1u);
  return (unsigned short)(r >> 16);
}
__device__ __forceinline__ float bf2f(unsigned short s) {
  return __uint_as_float(((unsigned)s) << 16);
}
__device__ __forceinline__ void gload_lds16(const void* g, void* l) {
  __builtin_amdgcn_global_load_lds(
      (const __attribute__((address_space(1))) unsigned int*)g,
      (__attribute__((address_space(3))) unsigned int*)l, 16, 0, 0);
}

#define TM 128
#define TN 128
#define GH 7  // y-tiles grouped per rasterization column (L2 locality)

// NT MFMA GEMM: A [M][K] (ld=ldA), B [N][K] (ld=ldB), both as NSPLIT bf16 planes.
// 1D grid = GX*GY*GZ blocks (divisible by 8), XCD-chunked + grouped raster.
// K-loop: TK=16, double-buffered LDS, stage(k+1) before compute(k) (min-2-phase).
// MODE: 0=XC 1=QKV 2=S 3=OUT
template<int NSPLIT, int MODE>
__global__ __launch_bounds__(256, 3) void mfma_gemm(
    const unsigned short* __restrict__ A0, const unsigned short* __restrict__ A1,
    const unsigned short* __restrict__ A2,
    const unsigned short* __restrict__ B0, const unsigned short* __restrict__ B1,
    const unsigned short* __restrict__ B2,
    int GX, int GY,
    int M, int N, int K, int ldA, int ldB, long sA, long sB,
    const float* __restrict__ bias, float alpha,
    float* __restrict__ outF, long sOutF,
    unsigned short* __restrict__ P0, unsigned short* __restrict__ P1,
    unsigned short* __restrict__ P2, long sP,
    unsigned short* __restrict__ R0, unsigned short* __restrict__ R1,
    unsigned short* __restrict__ R2, long sR,
    unsigned short* __restrict__ V0, unsigned short* __restrict__ V1, long sV,
    unsigned short* __restrict__ xcn, long sXcn)
{
  __shared__ __align__(16) unsigned short As[2][NSPLIT][128 * 16];
  __shared__ __align__(16) unsigned short Bs[2][NSPLIT][128 * 16];

  const int tid = threadIdx.x;

  // ---- XCD-chunked bijective remap (total % 8 == 0) + grouped raster decode
  const int total = GX * GY * ((int)gridDim.x / (GX * GY));
  const int q = total >> 3;
  const int wg = blockIdx.x;
  const int c = (wg & 7) * q + (wg >> 3);
  const int pb = GX * GY;
  const int bz = c / pb;
  int r = c - bz * pb;
  const int gy = r / (GH * GX);
  int rr = r - gy * (GH * GX);
  const int hh = min(GH, GY - gy * GH);
  const int xt = rr / hh;
  const int yt = gy * GH + (rr - xt * hh);

  const int m0 = yt * TM, n0 = xt * TN;
  const int lane = tid & 63, w = tid >> 6;
  const int wm = w >> 1, wn = w & 1;
  const int g = lane >> 5, lr = lane & 31;

  // staging: thread -> (row = tid>>1, 16B half = tid&1); LDS dest linear tid*16
  const long aoff = (long)min(m0 + (tid >> 1), M - 1) * ldA + (tid & 1) * 8;
  const long boff = (long)min(n0 + (tid >> 1), N - 1) * ldB + (tid & 1) * 8;

  const unsigned short* Ap[3];
  const unsigned short* Bp[3];
  Ap[0] = A0 + bz * sA; Bp[0] = B0 + bz * sB;
  Ap[1] = A1 + bz * sA; Bp[1] = B1 + bz * sB;
  Ap[2] = (NSPLIT == 3) ? A2 + bz * sA : Ap[0];
  Bp[2] = (NSPLIT == 3) ? B2 + bz * sB : Bp[0];

  f32x16 acc[2][2];
#pragma unroll
  for (int i = 0; i < 2; i++)
#pragma unroll
    for (int j = 0; j < 2; j++)
#pragma unroll
      for (int e = 0; e < 16; e++) acc[i][j][e] = 0.f;

  const int NT = K >> 4;

  // ---- prologue: stage tile 0 into buf 0
#pragma unroll
  for (int p = 0; p < NSPLIT; p++) {
    gload_lds16(Ap[p] + aoff, (char*)&As[0][p][0] + tid * 16);
    gload_lds16(Bp[p] + boff, (char*)&Bs[0][p][0] + tid * 16);
  }
  __syncthreads();  // compiler inserts vmcnt(0) drain here

  int cur = 0;
  for (int kt = 0; kt < NT; kt++) {
    // ---- stage next tile into the other buffer (overlaps compute below)
    if (kt + 1 < NT) {
      const long k0 = (long)(kt + 1) << 4;
#pragma unroll
      for (int p = 0; p < NSPLIT; p++) {
        gload_lds16(Ap[p] + aoff + k0, (char*)&As[cur ^ 1][p][0] + tid * 16);
        gload_lds16(Bp[p] + boff + k0, (char*)&Bs[cur ^ 1][p][0] + tid * 16);
      }
    }
    // ---- fragments from current buffer
    short8 af[2][NSPLIT], bf[2][NSPLIT];
#pragma unroll
    for (int i = 0; i < 2; i++) {
      const int rowa = wm * 64 + i * 32 + lr;
      const int rowb = wn * 64 + i * 32 + lr;
#pragma unroll
      for (int p = 0; p < NSPLIT; p++) {
        af[i][p] = *(const short8*)&As[cur][p][rowa * 16 + g * 8];
        bf[i][p] = *(const short8*)&Bs[cur][p][rowb * 16 + g * 8];
      }
    }
    __builtin_amdgcn_s_setprio(1);
#pragma unroll
    for (int i = 0; i < 2; i++)
#pragma unroll
      for (int j = 0; j < 2; j++) {
        acc[i][j] = __builtin_amdgcn_mfma_f32_32x32x16_bf16(af[i][0], bf[j][0], acc[i][j], 0, 0, 0);
        acc[i][j] = __builtin_amdgcn_mfma_f32_32x32x16_bf16(af[i][0], bf[j][1], acc[i][j], 0, 0, 0);
        acc[i][j] = __builtin_amdgcn_mfma_f32_32x32x16_bf16(af[i][1], bf[j][0], acc[i][j], 0, 0, 0);
        if (NSPLIT == 3) {
          acc[i][j] = __builtin_amdgcn_mfma_f32_32x32x16_bf16(af[i][1], bf[j][1], acc[i][j], 0, 0, 0);
          acc[i][j] = __builtin_amdgcn_mfma_f32_32x32x16_bf16(af[i][0], bf[j][2], acc[i][j], 0, 0, 0);
          acc[i][j] = __builtin_amdgcn_mfma_f32_32x32x16_bf16(af[i][2], bf[j][0], acc[i][j], 0, 0, 0);
        }
      }
    __builtin_amdgcn_s_setprio(0);
    __syncthreads();  // vmcnt(0)+lgkmcnt(0) drain: next buffer now fully landed
    cur ^= 1;
  }

  // epilogue: row = m0+wm*64+i*32 + rq*8 + g*4 + t ; col = n0+wn*64+j*32+lr
#pragma unroll
  for (int i = 0; i < 2; i++)
#pragma unroll
    for (int j = 0; j < 2; j++) {
      const int cb = n0 + wn * 64 + j * 32;
      const int col = cb + lr;
#pragma unroll
      for (int rq = 0; rq < 4; rq++)
#pragma unroll
        for (int t = 0; t < 4; t++) {
          const int reg = rq * 4 + t;
          const int row = m0 + wm * 64 + i * 32 + rq * 8 + g * 4 + t;
          float v = acc[i][j][reg];
          if (MODE == 0) {  // XC: relu, 3-plane xcT [n][c] + bf16 xc_cn [c][n]
            if (row < M) {
              v += bias[col];
              v = fmaxf(v, 0.f);
              const unsigned short h = f2bf(v); const float hf = bf2f(h);
              const unsigned short m_ = f2bf(v - hf); const float mf = bf2f(m_);
              const unsigned short l = f2bf(v - hf - mf);
              const long o = bz * sP + (long)row * 512 + col;
              P0[o] = h; P1[o] = m_; P2[o] = l;
              xcn[bz * sXcn + (long)col * 1600 + row] = h;
            }
          } else if (MODE == 1) {  // QKV
            if (row < M) {
              v += bias[col];
              if (cb < 512) {
                const unsigned short h = f2bf(v); const float hf = bf2f(h);
                const unsigned short m_ = f2bf(v - hf); const float mf = bf2f(m_);
                const unsigned short l = f2bf(v - hf - mf);
                const long o = bz * sP + (long)row * 512 + col;
                P0[o] = h; P1[o] = m_; P2[o] = l;
              } else if (cb < 1024) {
                const unsigned short h = f2bf(v); const float hf = bf2f(h);
                const unsigned short m_ = f2bf(v - hf); const float mf = bf2f(m_);
                const unsigned short l = f2bf(v - hf - mf);
                const long o = bz * sR + (long)row * 512 + (col - 512);
                R0[o] = h; R1[o] = m_; R2[o] = l;
              } else {
                const unsigned short h = f2bf(v);
                const unsigned short l = f2bf(v - bf2f(h));
                const long o = bz * sV + (long)(col - 1024) * 1600 + row;
                V0[o] = h; V1[o] = l;
              }
            }
          } else if (MODE == 2) {  // S
            if (row < M && col < N)
              outF[bz * sOutF + (long)row * 1600 + col] = v * alpha;
          } else {  // OUT: += residual
            if (col < N) {
              v += bf2f(xcn[bz * sXcn + (long)row * 1600 + col]);
              outF[bz * sOutF + (long)row * 1600 + col] = v;
            }
          }
        }
    }
}

// x [B][C][N] f32 -> xT planes [B][N][C] bf16 h/m/l
__global__ __launch_bounds__(256) void transpose_split_x(
    const float* __restrict__ x, unsigned short* __restrict__ X0,
    unsigned short* __restrict__ X1, unsigned short* __restrict__ X2)
{
  __shared__ float t[32][33];
  const int bz = blockIdx.z;
  const int n0 = blockIdx.x * 32, c0 = blockIdx.y * 32;
  const int tx = threadIdx.x & 31, ty = threadIdx.x >> 5;
  const float* xb = x + (long)bz * 512 * 1600;
#pragma unroll
  for (int k = 0; k < 4; k++)
    t[ty + k * 8][tx] = xb[(long)(c0 + ty + k * 8) * 1600 + n0 + tx];
  __syncthreads();
  const long ob = (long)bz * 1600 * 512;
#pragma unroll
  for (int k = 0; k < 4; k++) {
    const float v = t[tx][ty + k * 8];
    const unsigned short h = f2bf(v); const float hf = bf2f(h);
    const unsigned short m_ = f2bf(v - hf); const float mf = bf2f(m_);
    const unsigned short l = f2bf(v - hf - mf);
    const long o = ob + (long)(n0 + ty + k * 8) * 512 + c0 + tx;
    X0[o] = h; X1[o] = m_; X2[o] = l;
  }
}

__global__ __launch_bounds__(256) void split3_mat(
    const float* __restrict__ W, unsigned short* __restrict__ H,
    unsigned short* __restrict__ Mp, unsigned short* __restrict__ L, int n)
{
  const int i = blockIdx.x * 256 + threadIdx.x;
  if (i < n) {
    const float v = W[i];
    const unsigned short h = f2bf(v); const float hf = bf2f(h);
    const unsigned short m_ = f2bf(v - hf); const float mf = bf2f(m_);
    H[i] = h; Mp[i] = m_; L[i] = f2bf(v - hf - mf);
  }
}

// W' = W2 @ W1 (512^3, fp32 vector), split-written into planes at row offset
__global__ __launch_bounds__(256) void combine_gemm(
    const float* __restrict__ A, const float* __restrict__ B,
    unsigned short* __restrict__ H, unsigned short* __restrict__ Mp,
    unsigned short* __restrict__ L, int rowoff)
{
  __shared__ float As[16][68];
  __shared__ float Bs[16][68];
  const int tid = threadIdx.x;
  const int m0 = blockIdx.y * 64, n0 = blockIdx.x * 64;
  const int tx = tid & 15, ty = tid >> 4;
  float acc[4][4];
#pragma unroll
  for (int i = 0; i < 4; i++)
#pragma unroll
    for (int j = 0; j < 4; j++) acc[i][j] = 0.f;
  for (int k0 = 0; k0 < 512; k0 += 16) {
    {
      const int cA = tid & 15, r0 = tid >> 4;
#pragma unroll
      for (int l = 0; l < 4; l++)
        As[cA][r0 + 16 * l] = A[(long)(m0 + r0 + 16 * l) * 512 + (k0 + cA)];
      const int c2 = tid & 63, r2 = tid >> 6;
#pragma unroll
      for (int l = 0; l < 4; l++)
        Bs[r2 + 4 * l][c2] = B[(long)(k0 + r2 + 4 * l) * 512 + (n0 + c2)];
    }
    __syncthreads();
#pragma unroll
    for (int kk = 0; kk < 16; kk++) {
      float a[4], b[4];
#pragma unroll
      for (int i = 0; i < 4; i++) a[i] = As[kk][ty * 4 + i];
#pragma unroll
      for (int j = 0; j < 4; j++) b[j] = Bs[kk][tx * 4 + j];
#pragma unroll
      for (int i = 0; i < 4; i++)
#pragma unroll
        for (int j = 0; j < 4; j++) acc[i][j] = fmaf(a[i], b[j], acc[i][j]);
    }
    __syncthreads();
  }
#pragma unroll
  for (int i = 0; i < 4; i++) {
    const int m = rowoff + m0 + ty * 4 + i;
#pragma unroll
    for (int j = 0; j < 4; j++) {
      const int n = n0 + tx * 4 + j;
      const float v = acc[i][j];
      const unsigned short h = f2bf(v); const float hf = bf2f(h);
      const unsigned short m_ = f2bf(v - hf); const float mf = bf2f(m_);
      const long o = (long)m * 512 + n;
      H[o] = h; Mp[o] = m_; L[o] = f2bf(v - hf - mf);
    }
  }
}

__global__ __launch_bounds__(256) void bias_combine(
    const float* __restrict__ W2, const float* __restrict__ b1,
    const float* __restrict__ b2, float* __restrict__ bout)
{
  const int o = blockIdx.x * 256 + threadIdx.x;
  if (o < 512) {
    float acc = b2[o];
    for (int t = 0; t < 512; t++) acc = fmaf(W2[(long)o * 512 + t], b1[t], acc);
    bout[o] = acc;
  }
}

#define NROW 1600
#define NB 1024
#define BOFF 3392

// softmax + rank mask; reads S row fp32, writes w = attn*mask as TWO bf16 planes
// in place: row n occupies bf16[0..1599]=h, bf16[1600..3199]=l of the old fp32 row.
__global__ __launch_bounds__(256) void rowproc(float* __restrict__ S)
{
  __shared__ float sm[NROW];
  __shared__ float wmask[NROW];
  __shared__ unsigned short gidx[NROW];
  __shared__ int hist[NB];
  __shared__ int Rb[NB];
  __shared__ int scA[256];
  __shared__ int scB[256];
  __shared__ float redf[256];

  const int tid = threadIdx.x;
  float* srow = S + (long)blockIdx.x * NROW;

  float lmax = -3.4e38f;
  for (int i = tid; i < NROW; i += 256) {
    const float v = srow[i];
    sm[i] = v;
    wmask[i] = 1.f;
    lmax = fmaxf(lmax, v);
  }
  redf[tid] = lmax;
#pragma unroll
  for (int j = 0; j < NB / 256; j++) hist[tid + 256 * j] = 0;
  __syncthreads();
#pragma unroll
  for (int s = 128; s > 0; s >>= 1) {
    if (tid < s) redf[tid] = fmaxf(redf[tid], redf[tid + s]);
    __syncthreads();
  }
  const float rmax = redf[0];
  __syncthreads();

  float lsum = 0.f;
  for (int i = tid; i < NROW; i += 256) {
    const float v = sm[i];
    lsum += __expf(v - rmax);
    if (v >= 0.f) {
      unsigned u = __float_as_uint(v) & 0x7fffffffu;
      int b = (int)(u >> 18) - BOFF;
      b = max(0, min(NB - 1, b));
      atomicAdd(&hist[b], 1);
    }
  }
  redf[tid] = lsum;
  __syncthreads();
#pragma unroll
  for (int s = 128; s > 0; s >>= 1) {
    if (tid < s) redf[tid] += redf[tid + s];
    __syncthreads();
  }
  const float Z = redf[0];

  const int h0 = hist[4 * tid], h1 = hist[4 * tid + 1];
  const int h2 = hist[4 * tid + 2], h3 = hist[4 * tid + 3];
  const int local = h0 + h1 + h2 + h3;
  scA[tid] = local;
  __syncthreads();
  int* src = scA;
  int* dst = scB;
#pragma unroll
  for (int d = 1; d < 256; d <<= 1) {
    const int v = src[tid] + ((tid + d < 256) ? src[tid + d] : 0);
    dst[tid] = v;
    __syncthreads();
    int* tp = src; src = dst; dst = tp;
  }
  const int P = src[0];
  const int hi = src[tid] - local;
  Rb[4 * tid + 3] = hi;
  Rb[4 * tid + 2] = hi + h3;
  Rb[4 * tid + 1] = hi + h3 + h2;
  Rb[4 * tid + 0] = hi + h3 + h2 + h1;
  __syncthreads();

  for (int i = tid; i < NROW; i += 256) {
    const float v = sm[i];
    if (v >= 0.f) {
      unsigned u = __float_as_uint(v) & 0x7fffffffu;
      int b = (int)(u >> 18) - BOFF;
      b = max(0, min(NB - 1, b));
      gidx[atomicAdd(&Rb[b], 1)] = (unsigned short)i;
    }
  }
  __syncthreads();

  for (int p = tid; p < P; p += 256) {
    const int ip = gidx[p];
    const float vp = sm[ip];
    unsigned u = __float_as_uint(vp) & 0x7fffffffu;
    int b = (int)(u >> 18) - BOFF;
    b = max(0, min(NB - 1, b));
    const int end = Rb[b];
    const int start = end - hist[b];
    int cnt = 0;
    for (int qq = start; qq < end; qq++) {
      const int iq = gidx[qq];
      const float vq = sm[iq];
      cnt += (int)((vq > vp) || ((vq == vp) && (iq < ip)));
    }
    const float r1 = (float)(start + cnt + 1);
    wmask[ip] = r1 * r1 * r1;
  }
  __syncthreads();

  const float invZ = 1.f / Z;
  unsigned short* wrow = (unsigned short*)srow;
  for (int i = tid; i < NROW; i += 256) {
    const float val = __expf(sm[i] - rmax) * invZ * wmask[i];
    const unsigned short h = f2bf(val);
    wrow[i] = h;
    wrow[NROW + i] = f2bf(val - bf2f(h));
  }
}

extern "C" void kernel_launch(void* const* d_in, const int* in_sizes, int n_in,
                              void* d_out, int out_size, void* d_ws, size_t ws_size,
                              hipStream_t stream)
{
  const float scale = 0.04419417382415922f;  // 1/sqrt(512)
  const long sCN = 819200L;                  // 512*1600
  const long sNN = 2560000L;                 // 1600*1600
  const long ePlane = 8L * sCN;              // elems per bf16 plane (batched)

  const float* x   = (const float*)d_in[0];
  const float* Wc  = (const float*)d_in[1];
  const float* bc  = (const float*)d_in[2];
  const float* Wq1 = (const float*)d_in[3];
  const float* bq1 = (const float*)d_in[4];
  const float* Wq2 = (const float*)d_in[5];
  const float* bq2 = (const float*)d_in[6];
  const float* Wk1 = (const float*)d_in[7];
  const float* bk1 = (const float*)d_in[8];
  const float* Wk2 = (const float*)d_in[9];
  const float* bk2 = (const float*)d_in[10];
  const float* Wv1 = (const float*)d_in[11];
  const float* bv1 = (const float*)d_in[12];
  const float* Wv2 = (const float*)d_in[13];
  const float* bv2 = (const float*)d_in[14];
  float* out = (float*)d_out;

  char* p = (char*)d_ws;
  auto carve = [&](size_t bytes) { char* r = p; p += (bytes + 255) & ~255UL; return r; };

  float* S = (float*)carve(8L * sNN * 4);  // S fp32; also hosts xT planes early, w planes late
  unsigned short* Xh = (unsigned short*)S;
  unsigned short* Xm = Xh + ePlane;
  unsigned short* Xl = Xm + ePlane;
  unsigned short* xcTh = (unsigned short*)carve(ePlane * 2);
  unsigned short* xcTm = (unsigned short*)carve(ePlane * 2);
  unsigned short* xcTl = (unsigned short*)carve(ePlane * 2);
  unsigned short* QTh = (unsigned short*)carve(ePlane * 2);
  unsigned short* QTm = (unsigned short*)carve(ePlane * 2);
  unsigned short* QTl = (unsigned short*)carve(ePlane * 2);
  unsigned short* KTh = (unsigned short*)carve(ePlane * 2);
  unsigned short* KTm = (unsigned short*)carve(ePlane * 2);
  unsigned short* KTl = (unsigned short*)carve(ePlane * 2);
  unsigned short* Vh = (unsigned short*)carve(ePlane * 2);
  unsigned short* Vl = (unsigned short*)carve(ePlane * 2);
  unsigned short* xc_cn = (unsigned short*)carve(ePlane * 2);
  unsigned short* Wch = (unsigned short*)carve(512L * 512 * 2);
  unsigned short* Wcm = (unsigned short*)carve(512L * 512 * 2);
  unsigned short* Wcl = (unsigned short*)carve(512L * 512 * 2);
  unsigned short* Wh = (unsigned short*)carve(1536L * 512 * 2);
  unsigned short* Wm = (unsigned short*)carve(1536L * 512 * 2);
  unsigned short* Wl = (unsigned short*)carve(1536L * 512 * 2);
  float* bqkv = (float*)carve(1536L * 4);

  // prep: x transpose+split, Wc split, combined weights/biases
  transpose_split_x<<<dim3(50, 16, 8), 256, 0, stream>>>(x, Xh, Xm, Xl);
  split3_mat<<<dim3(1024), 256, 0, stream>>>(Wc, Wch, Wcm, Wcl, 512 * 512);
  combine_gemm<<<dim3(8, 8), 256, 0, stream>>>(Wq2, Wq1, Wh, Wm, Wl, 0);
  combine_gemm<<<dim3(8, 8), 256, 0, stream>>>(Wk2, Wk1, Wh, Wm, Wl, 512);
  combine_gemm<<<dim3(8, 8), 256, 0, stream>>>(Wv2, Wv1, Wh, Wm, Wl, 1024);
  bias_combine<<<dim3(2), 256, 0, stream>>>(Wq2, bq1, bq2, bqkv);
  bias_combine<<<dim3(2), 256, 0, stream>>>(Wk2, bk1, bk2, bqkv + 512);
  bias_combine<<<dim3(2), 256, 0, stream>>>(Wv2, bv1, bv2, bqkv + 1024);

  // xc = relu(xT . Wc^T + bc): [1600][512], writes xcT planes + xc_cn
  mfma_gemm<3, 0><<<dim3(4 * 13 * 8), 256, 0, stream>>>(
      Xh, Xm, Xl, Wch, Wcm, Wcl, 4, 13, 1600, 512, 512, 512, 512, sCN, 0L, bc, 1.f,
      nullptr, 0L, xcTh, xcTm, xcTl, sCN,
      nullptr, nullptr, nullptr, 0L, nullptr, nullptr, 0L, xc_cn, sCN);

  // fused QKV: [1600][1536]
  mfma_gemm<3, 1><<<dim3(12 * 13 * 8), 256, 0, stream>>>(
      xcTh, xcTm, xcTl, Wh, Wm, Wl, 12, 13, 1600, 1536, 512, 512, 512, sCN, 0L, bqkv, 1.f,
      nullptr, 0L, QTh, QTm, QTl, sCN, KTh, KTm, KTl, sCN, Vh, Vl, sCN, nullptr, 0L);

  // S = scale * QT . KT^T : [1600][1600] fp32
  mfma_gemm<3, 2><<<dim3(13 * 13 * 8), 256, 0, stream>>>(
      QTh, QTm, QTl, KTh, KTm, KTl, 13, 13, 1600, 1600, 512, 512, 512, sCN, sCN, nullptr, scale,
      S, sNN, nullptr, nullptr, nullptr, 0L,
      nullptr, nullptr, nullptr, 0L, nullptr, nullptr, 0L, nullptr, 0L);

  // softmax + rank mask; writes w h/l planes in place over S
  rowproc<<<dim3(12800), 256, 0, stream>>>(S);

  // out = V . w^T + xc : [512][1600] fp32 -> d_out
  mfma_gemm<2, 3><<<dim3(13 * 4 * 8), 256, 0, stream>>>(
      Vh, Vl, nullptr, (unsigned short*)S, (unsigned short*)S + 1600, nullptr,
      13, 4, 512, 1600, 1600, 1600, 3200, sCN, 2L * sNN, nullptr, 1.f,
      out, sCN, nullptr, nullptr, nullptr, 0L,
      nullptr, nullptr, nullptr, 0L, nullptr, nullptr, 0L, xc_cn, sCN);
}

// Round 6
// 652.379 us; speedup vs baseline: 1.2848x; 1.2848x over previous
//
#include <hip/hip_runtime.h>
#include <math.h>

typedef short short8 __attribute__((ext_vector_type(8)));
typedef float f32x16 __attribute__((ext_vector_type(16)));

__device__ __forceinline__ unsigned short f2bf(float f) {
  unsigned u = __float_as_uint(f);
  unsigned r = u + 0x7fffu + ((u >> 16) & 1u);
  return (unsigned short)(r >> 16);
}
__device__ __forceinline__ float bf2f(unsigned short s) {
  return __uint_as_float(((unsigned)s) << 16);
}
__device__ __forceinline__ void gload_lds16(const void* g, void* l) {
  __builtin_amdgcn_global_load_lds(
      (const __attribute__((address_space(1))) unsigned int*)g,
      (__attribute__((address_space(3))) unsigned int*)l, 16, 0, 0);
}

#define TM 128
#define TN 128
#define GH 7  // y-tiles grouped per rasterization column (L2 locality)

// NT MFMA GEMM, 2-plane split (v ~= h + m), 3 products: hh + hm + mh.
// A [M][K] (ld=ldA), B [N][K] (ld=ldB). TK=32, double-buffered LDS,
// stage(k+1) before compute(k); r4's conflict-free XOR-quad layout.
// 1D grid = GX*GY*GZ blocks (divisible by 8), XCD-chunked + grouped raster.
// MODE: 0=XC 1=QKV 2=S 3=OUT
template<int MODE>
__global__ __launch_bounds__(256, 2) void mfma_gemm(
    const unsigned short* __restrict__ A0, const unsigned short* __restrict__ A1,
    const unsigned short* __restrict__ B0, const unsigned short* __restrict__ B1,
    int GX, int GY,
    int M, int N, int K, int ldA, int ldB, long sA, long sB,
    const float* __restrict__ bias, float alpha,
    float* __restrict__ outF, long sOutF,
    unsigned short* __restrict__ P0, unsigned short* __restrict__ P1, long sP,
    unsigned short* __restrict__ R0, unsigned short* __restrict__ R1, long sR,
    unsigned short* __restrict__ V0, unsigned short* __restrict__ V1, long sV,
    unsigned short* __restrict__ xcn, long sXcn)
{
  // [buf][plane][128 rows x 32 k] ; 2*2*8KB*2 = 64 KB total
  __shared__ __align__(16) unsigned short As[2][2][128 * 32];
  __shared__ __align__(16) unsigned short Bs[2][2][128 * 32];

  const int tid = threadIdx.x;

  // ---- XCD-chunked bijective remap (total % 8 == 0) + grouped raster decode
  const int total = GX * GY * ((int)gridDim.x / (GX * GY));
  const int q = total >> 3;
  const int wg = blockIdx.x;
  const int c = (wg & 7) * q + (wg >> 3);
  const int pb = GX * GY;
  const int bz = c / pb;
  int r = c - bz * pb;
  const int gy = r / (GH * GX);
  int rr = r - gy * (GH * GX);
  const int hh = min(GH, GY - gy * GH);
  const int xt = rr / hh;
  const int yt = gy * GH + (rr - xt * hh);

  const int m0 = yt * TM, n0 = xt * TN;
  const int lane = tid & 63, w = tid >> 6;
  const int wm = w >> 1, wn = w & 1;
  const int g = lane >> 5, lr = lane & 31;

  // staging: issue i covers rows i*64 + (tid>>2), 16B slot tid&3; source
  // pre-swizzled so LDS slot s of row r holds k-chunk s ^ ((r>>1)&3)
  const int str = tid >> 2, sts = tid & 3;
  long aoff[2], boff[2];
#pragma unroll
  for (int i = 0; i < 2; i++) {
    const int rw = i * 64 + str;
    const int swc = (sts ^ ((rw >> 1) & 3)) * 8;
    aoff[i] = (long)min(m0 + rw, M - 1) * ldA + swc;
    boff[i] = (long)min(n0 + rw, N - 1) * ldB + swc;
  }
  const unsigned short* Ap[2] = {A0 + bz * sA, A1 + bz * sA};
  const unsigned short* Bp[2] = {B0 + bz * sB, B1 + bz * sB};

  f32x16 acc[2][2];
#pragma unroll
  for (int i = 0; i < 2; i++)
#pragma unroll
    for (int j = 0; j < 2; j++)
#pragma unroll
      for (int e = 0; e < 16; e++) acc[i][j][e] = 0.f;

  const int NT = K >> 5;

  // ---- prologue: stage tile 0 into buf 0
#pragma unroll
  for (int p = 0; p < 2; p++)
#pragma unroll
    for (int i = 0; i < 2; i++) {
      gload_lds16(Ap[p] + aoff[i], (char*)&As[0][p][0] + i * 4096 + tid * 16);
      gload_lds16(Bp[p] + boff[i], (char*)&Bs[0][p][0] + i * 4096 + tid * 16);
    }
  __syncthreads();

  int cur = 0;
  for (int kt = 0; kt < NT; kt++) {
    // ---- stage next tile into other buffer; lands during compute below
    if (kt + 1 < NT) {
      const long k0 = (long)(kt + 1) << 5;
#pragma unroll
      for (int p = 0; p < 2; p++)
#pragma unroll
        for (int i = 0; i < 2; i++) {
          gload_lds16(Ap[p] + aoff[i] + k0, (char*)&As[cur ^ 1][p][0] + i * 4096 + tid * 16);
          gload_lds16(Bp[p] + boff[i] + k0, (char*)&Bs[cur ^ 1][p][0] + i * 4096 + tid * 16);
        }
    }
    // ---- compute current buffer: 2 kk sub-steps of K=16
#pragma unroll
    for (int kk = 0; kk < 2; kk++) {
      short8 af[2][2], bf[2][2];
#pragma unroll
      for (int i = 0; i < 2; i++) {
        const int rowa = wm * 64 + i * 32 + lr;
        const int sla = ((kk * 2 + g) ^ ((rowa >> 1) & 3)) * 8;
#pragma unroll
        for (int p = 0; p < 2; p++)
          af[i][p] = *(const short8*)&As[cur][p][rowa * 32 + sla];
        const int rowb = wn * 64 + i * 32 + lr;
        const int slb = ((kk * 2 + g) ^ ((rowb >> 1) & 3)) * 8;
#pragma unroll
        for (int p = 0; p < 2; p++)
          bf[i][p] = *(const short8*)&Bs[cur][p][rowb * 32 + slb];
      }
      __builtin_amdgcn_s_setprio(1);
#pragma unroll
      for (int i = 0; i < 2; i++)
#pragma unroll
        for (int j = 0; j < 2; j++) {
          acc[i][j] = __builtin_amdgcn_mfma_f32_32x32x16_bf16(af[i][0], bf[j][0], acc[i][j], 0, 0, 0);
          acc[i][j] = __builtin_amdgcn_mfma_f32_32x32x16_bf16(af[i][0], bf[j][1], acc[i][j], 0, 0, 0);
          acc[i][j] = __builtin_amdgcn_mfma_f32_32x32x16_bf16(af[i][1], bf[j][0], acc[i][j], 0, 0, 0);
        }
      __builtin_amdgcn_s_setprio(0);
    }
    __syncthreads();  // drains staging (in flight ~whole compute phase)
    cur ^= 1;
  }

  // epilogue: row = m0+wm*64+i*32 + rq*8 + g*4 + t ; col = n0+wn*64+j*32+lr
#pragma unroll
  for (int i = 0; i < 2; i++)
#pragma unroll
    for (int j = 0; j < 2; j++) {
      const int cb = n0 + wn * 64 + j * 32;
      const int col = cb + lr;
#pragma unroll
      for (int rq = 0; rq < 4; rq++)
#pragma unroll
        for (int t = 0; t < 4; t++) {
          const int reg = rq * 4 + t;
          const int row = m0 + wm * 64 + i * 32 + rq * 8 + g * 4 + t;
          float v = acc[i][j][reg];
          if (MODE == 0) {  // XC: relu, 2-plane xcT [n][c] + bf16 xc_cn [c][n]
            if (row < M) {
              v += bias[col];
              v = fmaxf(v, 0.f);
              const unsigned short h = f2bf(v);
              const unsigned short m_ = f2bf(v - bf2f(h));
              const long o = bz * sP + (long)row * 512 + col;
              P0[o] = h; P1[o] = m_;
              xcn[bz * sXcn + (long)col * 1600 + row] = h;
            }
          } else if (MODE == 1) {  // QKV
            if (row < M) {
              v += bias[col];
              const unsigned short h = f2bf(v);
              const unsigned short m_ = f2bf(v - bf2f(h));
              if (cb < 512) {
                const long o = bz * sP + (long)row * 512 + col;
                P0[o] = h; P1[o] = m_;
              } else if (cb < 1024) {
                const long o = bz * sR + (long)row * 512 + (col - 512);
                R0[o] = h; R1[o] = m_;
              } else {
                const long o = bz * sV + (long)(col - 1024) * 1600 + row;
                V0[o] = h; V1[o] = m_;
              }
            }
          } else if (MODE == 2) {  // S
            if (row < M && col < N)
              outF[bz * sOutF + (long)row * 1600 + col] = v * alpha;
          } else {  // OUT: += residual
            if (col < N) {
              v += bf2f(xcn[bz * sXcn + (long)row * 1600 + col]);
              outF[bz * sOutF + (long)row * 1600 + col] = v;
            }
          }
        }
    }
}

// x [B][C][N] f32 -> xT planes [B][N][C] bf16 h/m
__global__ __launch_bounds__(256) void transpose_split_x(
    const float* __restrict__ x, unsigned short* __restrict__ X0,
    unsigned short* __restrict__ X1)
{
  __shared__ float t[32][33];
  const int bz = blockIdx.z;
  const int n0 = blockIdx.x * 32, c0 = blockIdx.y * 32;
  const int tx = threadIdx.x & 31, ty = threadIdx.x >> 5;
  const float* xb = x + (long)bz * 512 * 1600;
#pragma unroll
  for (int k = 0; k < 4; k++)
    t[ty + k * 8][tx] = xb[(long)(c0 + ty + k * 8) * 1600 + n0 + tx];
  __syncthreads();
  const long ob = (long)bz * 1600 * 512;
#pragma unroll
  for (int k = 0; k < 4; k++) {
    const float v = t[tx][ty + k * 8];
    const unsigned short h = f2bf(v);
    const unsigned short m_ = f2bf(v - bf2f(h));
    const long o = ob + (long)(n0 + ty + k * 8) * 512 + c0 + tx;
    X0[o] = h; X1[o] = m_;
  }
}

__global__ __launch_bounds__(256) void split2_mat(
    const float* __restrict__ W, unsigned short* __restrict__ H,
    unsigned short* __restrict__ Mp, int n)
{
  const int i = blockIdx.x * 256 + threadIdx.x;
  if (i < n) {
    const float v = W[i];
    const unsigned short h = f2bf(v);
    H[i] = h; Mp[i] = f2bf(v - bf2f(h));
  }
}

// W' = W2 @ W1 (512^3, fp32 vector), split-written into 2 planes at row offset
__global__ __launch_bounds__(256) void combine_gemm(
    const float* __restrict__ A, const float* __restrict__ B,
    unsigned short* __restrict__ H, unsigned short* __restrict__ Mp, int rowoff)
{
  __shared__ float As[16][68];
  __shared__ float Bs[16][68];
  const int tid = threadIdx.x;
  const int m0 = blockIdx.y * 64, n0 = blockIdx.x * 64;
  const int tx = tid & 15, ty = tid >> 4;
  float acc[4][4];
#pragma unroll
  for (int i = 0; i < 4; i++)
#pragma unroll
    for (int j = 0; j < 4; j++) acc[i][j] = 0.f;
  for (int k0 = 0; k0 < 512; k0 += 16) {
    {
      const int cA = tid & 15, r0 = tid >> 4;
#pragma unroll
      for (int l = 0; l < 4; l++)
        As[cA][r0 + 16 * l] = A[(long)(m0 + r0 + 16 * l) * 512 + (k0 + cA)];
      const int c2 = tid & 63, r2 = tid >> 6;
#pragma unroll
      for (int l = 0; l < 4; l++)
        Bs[r2 + 4 * l][c2] = B[(long)(k0 + r2 + 4 * l) * 512 + (n0 + c2)];
    }
    __syncthreads();
#pragma unroll
    for (int kk = 0; kk < 16; kk++) {
      float a[4], b[4];
#pragma unroll
      for (int i = 0; i < 4; i++) a[i] = As[kk][ty * 4 + i];
#pragma unroll
      for (int j = 0; j < 4; j++) b[j] = Bs[kk][tx * 4 + j];
#pragma unroll
      for (int i = 0; i < 4; i++)
#pragma unroll
        for (int j = 0; j < 4; j++) acc[i][j] = fmaf(a[i], b[j], acc[i][j]);
    }
    __syncthreads();
  }
#pragma unroll
  for (int i = 0; i < 4; i++) {
    const int m = rowoff + m0 + ty * 4 + i;
#pragma unroll
    for (int j = 0; j < 4; j++) {
      const int n = n0 + tx * 4 + j;
      const float v = acc[i][j];
      const unsigned short h = f2bf(v);
      const long o = (long)m * 512 + n;
      H[o] = h; Mp[o] = f2bf(v - bf2f(h));
    }
  }
}

__global__ __launch_bounds__(256) void bias_combine(
    const float* __restrict__ W2, const float* __restrict__ b1,
    const float* __restrict__ b2, float* __restrict__ bout)
{
  const int o = blockIdx.x * 256 + threadIdx.x;
  if (o < 512) {
    float acc = b2[o];
    for (int t = 0; t < 512; t++) acc = fmaf(W2[(long)o * 512 + t], b1[t], acc);
    bout[o] = acc;
  }
}

#define NROW 1600
#define NB 1024
#define BOFF 3392

// softmax + rank mask; reads S row fp32, writes w = attn*mask as TWO bf16 planes
// in place: row n occupies bf16[0..1599]=h, bf16[1600..3199]=l of the old fp32 row.
__global__ __launch_bounds__(256) void rowproc(float* __restrict__ S)
{
  __shared__ float sm[NROW];
  __shared__ float wmask[NROW];
  __shared__ unsigned short gidx[NROW];
  __shared__ int hist[NB];
  __shared__ int Rb[NB];
  __shared__ int scA[256];
  __shared__ int scB[256];
  __shared__ float redf[256];

  const int tid = threadIdx.x;
  float* srow = S + (long)blockIdx.x * NROW;

  float lmax = -3.4e38f;
  for (int i = tid; i < NROW; i += 256) {
    const float v = srow[i];
    sm[i] = v;
    wmask[i] = 1.f;
    lmax = fmaxf(lmax, v);
  }
  redf[tid] = lmax;
#pragma unroll
  for (int j = 0; j < NB / 256; j++) hist[tid + 256 * j] = 0;
  __syncthreads();
#pragma unroll
  for (int s = 128; s > 0; s >>= 1) {
    if (tid < s) redf[tid] = fmaxf(redf[tid], redf[tid + s]);
    __syncthreads();
  }
  const float rmax = redf[0];
  __syncthreads();

  float lsum = 0.f;
  for (int i = tid; i < NROW; i += 256) {
    const float v = sm[i];
    lsum += __expf(v - rmax);
    if (v >= 0.f) {
      unsigned u = __float_as_uint(v) & 0x7fffffffu;
      int b = (int)(u >> 18) - BOFF;
      b = max(0, min(NB - 1, b));
      atomicAdd(&hist[b], 1);
    }
  }
  redf[tid] = lsum;
  __syncthreads();
#pragma unroll
  for (int s = 128; s > 0; s >>= 1) {
    if (tid < s) redf[tid] += redf[tid + s];
    __syncthreads();
  }
  const float Z = redf[0];

  const int h0 = hist[4 * tid], h1 = hist[4 * tid + 1];
  const int h2 = hist[4 * tid + 2], h3 = hist[4 * tid + 3];
  const int local = h0 + h1 + h2 + h3;
  scA[tid] = local;
  __syncthreads();
  int* src = scA;
  int* dst = scB;
#pragma unroll
  for (int d = 1; d < 256; d <<= 1) {
    const int v = src[tid] + ((tid + d < 256) ? src[tid + d] : 0);
    dst[tid] = v;
    __syncthreads();
    int* tp = src; src = dst; dst = tp;
  }
  const int P = src[0];
  const int hi = src[tid] - local;
  Rb[4 * tid + 3] = hi;
  Rb[4 * tid + 2] = hi + h3;
  Rb[4 * tid + 1] = hi + h3 + h2;
  Rb[4 * tid + 0] = hi + h3 + h2 + h1;
  __syncthreads();

  for (int i = tid; i < NROW; i += 256) {
    const float v = sm[i];
    if (v >= 0.f) {
      unsigned u = __float_as_uint(v) & 0x7fffffffu;
      int b = (int)(u >> 18) - BOFF;
      b = max(0, min(NB - 1, b));
      gidx[atomicAdd(&Rb[b], 1)] = (unsigned short)i;
    }
  }
  __syncthreads();

  for (int p = tid; p < P; p += 256) {
    const int ip = gidx[p];
    const float vp = sm[ip];
    unsigned u = __float_as_uint(vp) & 0x7fffffffu;
    int b = (int)(u >> 18) - BOFF;
    b = max(0, min(NB - 1, b));
    const int end = Rb[b];
    const int start = end - hist[b];
    int cnt = 0;
    for (int qq = start; qq < end; qq++) {
      const int iq = gidx[qq];
      const float vq = sm[iq];
      cnt += (int)((vq > vp) || ((vq == vp) && (iq < ip)));
    }
    const float r1 = (float)(start + cnt + 1);
    wmask[ip] = r1 * r1 * r1;
  }
  __syncthreads();

  const float invZ = 1.f / Z;
  unsigned short* wrow = (unsigned short*)srow;
  for (int i = tid; i < NROW; i += 256) {
    const float val = __expf(sm[i] - rmax) * invZ * wmask[i];
    const unsigned short h = f2bf(val);
    wrow[i] = h;
    wrow[NROW + i] = f2bf(val - bf2f(h));
  }
}

extern "C" void kernel_launch(void* const* d_in, const int* in_sizes, int n_in,
                              void* d_out, int out_size, void* d_ws, size_t ws_size,
                              hipStream_t stream)
{
  const float scale = 0.04419417382415922f;  // 1/sqrt(512)
  const long sCN = 819200L;                  // 512*1600
  const long sNN = 2560000L;                 // 1600*1600
  const long ePlane = 8L * sCN;              // elems per bf16 plane (batched)

  const float* x   = (const float*)d_in[0];
  const float* Wc  = (const float*)d_in[1];
  const float* bc  = (const float*)d_in[2];
  const float* Wq1 = (const float*)d_in[3];
  const float* bq1 = (const float*)d_in[4];
  const float* Wq2 = (const float*)d_in[5];
  const float* bq2 = (const float*)d_in[6];
  const float* Wk1 = (const float*)d_in[7];
  const float* bk1 = (const float*)d_in[8];
  const float* Wk2 = (const float*)d_in[9];
  const float* bk2 = (const float*)d_in[10];
  const float* Wv1 = (const float*)d_in[11];
  const float* bv1 = (const float*)d_in[12];
  const float* Wv2 = (const float*)d_in[13];
  const float* bv2 = (const float*)d_in[14];
  float* out = (float*)d_out;

  char* p = (char*)d_ws;
  auto carve = [&](size_t bytes) { char* r = p; p += (bytes + 255) & ~255UL; return r; };

  float* S = (float*)carve(8L * sNN * 4);  // S fp32; hosts xT planes early, w planes late
  unsigned short* Xh = (unsigned short*)S;
  unsigned short* Xm = Xh + ePlane;
  unsigned short* xcTh = (unsigned short*)carve(ePlane * 2);
  unsigned short* xcTm = (unsigned short*)carve(ePlane * 2);
  unsigned short* QTh = (unsigned short*)carve(ePlane * 2);
  unsigned short* QTm = (unsigned short*)carve(ePlane * 2);
  unsigned short* KTh = (unsigned short*)carve(ePlane * 2);
  unsigned short* KTm = (unsigned short*)carve(ePlane * 2);
  unsigned short* Vh = (unsigned short*)carve(ePlane * 2);
  unsigned short* Vm = (unsigned short*)carve(ePlane * 2);
  unsigned short* xc_cn = (unsigned short*)carve(ePlane * 2);
  unsigned short* Wch = (unsigned short*)carve(512L * 512 * 2);
  unsigned short* Wcm = (unsigned short*)carve(512L * 512 * 2);
  unsigned short* Wh = (unsigned short*)carve(1536L * 512 * 2);
  unsigned short* Wm = (unsigned short*)carve(1536L * 512 * 2);
  float* bqkv = (float*)carve(1536L * 4);

  // prep: x transpose+split, Wc split, combined weights/biases
  transpose_split_x<<<dim3(50, 16, 8), 256, 0, stream>>>(x, Xh, Xm);
  split2_mat<<<dim3(1024), 256, 0, stream>>>(Wc, Wch, Wcm, 512 * 512);
  combine_gemm<<<dim3(8, 8), 256, 0, stream>>>(Wq2, Wq1, Wh, Wm, 0);
  combine_gemm<<<dim3(8, 8), 256, 0, stream>>>(Wk2, Wk1, Wh, Wm, 512);
  combine_gemm<<<dim3(8, 8), 256, 0, stream>>>(Wv2, Wv1, Wh, Wm, 1024);
  bias_combine<<<dim3(2), 256, 0, stream>>>(Wq2, bq1, bq2, bqkv);
  bias_combine<<<dim3(2), 256, 0, stream>>>(Wk2, bk1, bk2, bqkv + 512);
  bias_combine<<<dim3(2), 256, 0, stream>>>(Wv2, bv1, bv2, bqkv + 1024);

  // xc = relu(xT . Wc^T + bc): [1600][512], writes xcT planes + xc_cn
  mfma_gemm<0><<<dim3(4 * 13 * 8), 256, 0, stream>>>(
      Xh, Xm, Wch, Wcm, 4, 13, 1600, 512, 512, 512, 512, sCN, 0L, bc, 1.f,
      nullptr, 0L, xcTh, xcTm, sCN, nullptr, nullptr, 0L, nullptr, nullptr, 0L,
      xc_cn, sCN);

  // fused QKV: [1600][1536]
  mfma_gemm<1><<<dim3(12 * 13 * 8), 256, 0, stream>>>(
      xcTh, xcTm, Wh, Wm, 12, 13, 1600, 1536, 512, 512, 512, sCN, 0L, bqkv, 1.f,
      nullptr, 0L, QTh, QTm, sCN, KTh, KTm, sCN, Vh, Vm, sCN, nullptr, 0L);

  // S = scale * QT . KT^T : [1600][1600] fp32
  mfma_gemm<2><<<dim3(13 * 13 * 8), 256, 0, stream>>>(
      QTh, QTm, KTh, KTm, 13, 13, 1600, 1600, 512, 512, 512, sCN, sCN, nullptr, scale,
      S, sNN, nullptr, nullptr, 0L, nullptr, nullptr, 0L, nullptr, nullptr, 0L,
      nullptr, 0L);

  // softmax + rank mask; writes w h/l planes in place over S
  rowproc<<<dim3(12800), 256, 0, stream>>>(S);

  // out = V . w^T + xc : [512][1600] fp32 -> d_out
  mfma_gemm<3><<<dim3(13 * 4 * 8), 256, 0, stream>>>(
      Vh, Vm, (unsigned short*)S, (unsigned short*)S + 1600,
      13, 4, 512, 1600, 1600, 1600, 3200, sCN, 2L * sNN, nullptr, 1.f,
      out, sCN, nullptr, nullptr, 0L, nullptr, nullptr, 0L, nullptr, nullptr, 0L,
      xc_cn, sCN);
}

// Round 7
// 613.091 us; speedup vs baseline: 1.3671x; 1.0641x over previous
//
#include <hip/hip_runtime.h>
#include <math.h>

typedef short short8 __attribute__((ext_vector_type(8)));
typedef float f32x16 __attribute__((ext_vector_type(16)));

__device__ __forceinline__ unsigned short f2bf(float f) {
  unsigned u = __float_as_uint(f);
  unsigned r = u + 0x7fffu + ((u >> 16) & 1u);
  return (unsigned short)(r >> 16);
}
__device__ __forceinline__ float bf2f(unsigned short s) {
  return __uint_as_float(((unsigned)s) << 16);
}
__device__ __forceinline__ void gload_lds16(const void* g, void* l) {
  __builtin_amdgcn_global_load_lds(
      (const __attribute__((address_space(1))) unsigned int*)g,
      (__attribute__((address_space(3))) unsigned int*)l, 16, 0, 0);
}

#define TM 128
#define TN 128
#define GH 7  // y-tiles grouped per rasterization column (L2 locality)

// NT MFMA GEMM, 2-plane split (v ~= h + m), 3 products: hh + hm + mh.
// A [M][K] (ld=ldA), B [N][K] (ld=ldB). TK=32, SINGLE-buffer LDS (32 KB ->
// 4-5 blocks/CU; implicit cross-block overlap hides the vmcnt drain).
// 1D grid = GX*GY*GZ blocks (divisible by 8), XCD-chunked + grouped raster.
// MODE: 0=XC 1=QKV 2=S 3=OUT
template<int MODE>
__global__ __launch_bounds__(256, 4) void mfma_gemm(
    const unsigned short* __restrict__ A0, const unsigned short* __restrict__ A1,
    const unsigned short* __restrict__ B0, const unsigned short* __restrict__ B1,
    int GX, int GY,
    int M, int N, int K, int ldA, int ldB, long sA, long sB,
    const float* __restrict__ bias, float alpha,
    float* __restrict__ outF, long sOutF,
    unsigned short* __restrict__ P0, unsigned short* __restrict__ P1, long sP,
    unsigned short* __restrict__ R0, unsigned short* __restrict__ R1, long sR,
    unsigned short* __restrict__ V0, unsigned short* __restrict__ V1, long sV,
    const unsigned short* __restrict__ xcn, long sXcn)
{
  // [plane][128 rows x 32 k] ; 2*8KB*2 = 32 KB total
  __shared__ __align__(16) unsigned short As[2][128 * 32];
  __shared__ __align__(16) unsigned short Bs[2][128 * 32];

  const int tid = threadIdx.x;

  // ---- XCD-chunked bijective remap (total % 8 == 0) + grouped raster decode
  const int total = GX * GY * ((int)gridDim.x / (GX * GY));
  const int q = total >> 3;
  const int wg = blockIdx.x;
  const int c = (wg & 7) * q + (wg >> 3);
  const int pb = GX * GY;
  const int bz = c / pb;
  int r = c - bz * pb;
  const int gy = r / (GH * GX);
  int rr = r - gy * (GH * GX);
  const int hh = min(GH, GY - gy * GH);
  const int xt = rr / hh;
  const int yt = gy * GH + (rr - xt * hh);

  const int m0 = yt * TM, n0 = xt * TN;
  const int lane = tid & 63, w = tid >> 6;
  const int wm = w >> 1, wn = w & 1;
  const int g = lane >> 5, lr = lane & 31;

  // staging: issue i covers rows i*64 + (tid>>2), 16B slot tid&3; source
  // pre-swizzled so LDS slot s of row r holds k-chunk s ^ ((r>>1)&3)
  const int str = tid >> 2, sts = tid & 3;
  long aoff[2], boff[2];
#pragma unroll
  for (int i = 0; i < 2; i++) {
    const int rw = i * 64 + str;
    const int swc = (sts ^ ((rw >> 1) & 3)) * 8;
    aoff[i] = (long)min(m0 + rw, M - 1) * ldA + swc;
    boff[i] = (long)min(n0 + rw, N - 1) * ldB + swc;
  }
  const unsigned short* Ap[2] = {A0 + bz * sA, A1 + bz * sA};
  const unsigned short* Bp[2] = {B0 + bz * sB, B1 + bz * sB};

  f32x16 acc[2][2];
#pragma unroll
  for (int i = 0; i < 2; i++)
#pragma unroll
    for (int j = 0; j < 2; j++)
#pragma unroll
      for (int e = 0; e < 16; e++) acc[i][j][e] = 0.f;

  const int NT = K >> 5;

  for (int kt = 0; kt < NT; kt++) {
    const long k0 = (long)kt << 5;
    if (kt) __syncthreads();  // previous compute done before overwrite
#pragma unroll
    for (int p = 0; p < 2; p++)
#pragma unroll
      for (int i = 0; i < 2; i++) {
        gload_lds16(Ap[p] + aoff[i] + k0, (char*)&As[p][0] + i * 4096 + tid * 16);
        gload_lds16(Bp[p] + boff[i] + k0, (char*)&Bs[p][0] + i * 4096 + tid * 16);
      }
    __syncthreads();  // drain staging; other resident blocks compute meanwhile

#pragma unroll
    for (int kk = 0; kk < 2; kk++) {
      short8 af[2][2], bf[2][2];
#pragma unroll
      for (int i = 0; i < 2; i++) {
        const int rowa = wm * 64 + i * 32 + lr;
        const int sla = ((kk * 2 + g) ^ ((rowa >> 1) & 3)) * 8;
#pragma unroll
        for (int p = 0; p < 2; p++)
          af[i][p] = *(const short8*)&As[p][rowa * 32 + sla];
        const int rowb = wn * 64 + i * 32 + lr;
        const int slb = ((kk * 2 + g) ^ ((rowb >> 1) & 3)) * 8;
#pragma unroll
        for (int p = 0; p < 2; p++)
          bf[i][p] = *(const short8*)&Bs[p][rowb * 32 + slb];
      }
      __builtin_amdgcn_s_setprio(1);
#pragma unroll
      for (int i = 0; i < 2; i++)
#pragma unroll
        for (int j = 0; j < 2; j++) {
          acc[i][j] = __builtin_amdgcn_mfma_f32_32x32x16_bf16(af[i][0], bf[j][0], acc[i][j], 0, 0, 0);
          acc[i][j] = __builtin_amdgcn_mfma_f32_32x32x16_bf16(af[i][0], bf[j][1], acc[i][j], 0, 0, 0);
          acc[i][j] = __builtin_amdgcn_mfma_f32_32x32x16_bf16(af[i][1], bf[j][0], acc[i][j], 0, 0, 0);
        }
      __builtin_amdgcn_s_setprio(0);
    }
  }

  // epilogue: row = m0+wm*64+i*32 + rq*8 + g*4 + t ; col = n0+wn*64+j*32+lr
#pragma unroll
  for (int i = 0; i < 2; i++)
#pragma unroll
    for (int j = 0; j < 2; j++) {
      const int cb = n0 + wn * 64 + j * 32;
      const int col = cb + lr;
#pragma unroll
      for (int rq = 0; rq < 4; rq++)
#pragma unroll
        for (int t = 0; t < 4; t++) {
          const int reg = rq * 4 + t;
          const int row = m0 + wm * 64 + i * 32 + rq * 8 + g * 4 + t;
          float v = acc[i][j][reg];
          if (MODE == 0) {  // XC: relu, 2-plane xcT [n][c]
            if (row < M) {
              v += bias[col];
              v = fmaxf(v, 0.f);
              const unsigned short h = f2bf(v);
              const unsigned short m_ = f2bf(v - bf2f(h));
              const long o = bz * sP + (long)row * 512 + col;
              P0[o] = h; P1[o] = m_;
            }
          } else if (MODE == 1) {  // QKV: all segments [n][c] coalesced
            if (row < M) {
              v += bias[col];
              const unsigned short h = f2bf(v);
              const unsigned short m_ = f2bf(v - bf2f(h));
              const int sc = col & 511;
              if (cb < 512) {
                const long o = bz * sP + (long)row * 512 + sc;
                P0[o] = h; P1[o] = m_;
              } else if (cb < 1024) {
                const long o = bz * sR + (long)row * 512 + sc;
                R0[o] = h; R1[o] = m_;
              } else {
                const long o = bz * sV + (long)row * 512 + sc;
                V0[o] = h; V1[o] = m_;
              }
            }
          } else if (MODE == 2) {  // S
            if (row < M && col < N)
              outF[bz * sOutF + (long)row * 1600 + col] = v * alpha;
          } else {  // OUT: += residual (xc_cn bf16, coalesced)
            if (col < N) {
              v += bf2f(xcn[bz * sXcn + (long)row * 1600 + col]);
              outF[bz * sOutF + (long)row * 1600 + col] = v;
            }
          }
        }
    }
}

// x [B][C][N] f32 -> xT planes [B][N][C] bf16 h/m
__global__ __launch_bounds__(256) void transpose_split_x(
    const float* __restrict__ x, unsigned short* __restrict__ X0,
    unsigned short* __restrict__ X1)
{
  __shared__ float t[32][33];
  const int bz = blockIdx.z;
  const int n0 = blockIdx.x * 32, c0 = blockIdx.y * 32;
  const int tx = threadIdx.x & 31, ty = threadIdx.x >> 5;
  const float* xb = x + (long)bz * 512 * 1600;
#pragma unroll
  for (int k = 0; k < 4; k++)
    t[ty + k * 8][tx] = xb[(long)(c0 + ty + k * 8) * 1600 + n0 + tx];
  __syncthreads();
  const long ob = (long)bz * 1600 * 512;
#pragma unroll
  for (int k = 0; k < 4; k++) {
    const float v = t[tx][ty + k * 8];
    const unsigned short h = f2bf(v);
    const unsigned short m_ = f2bf(v - bf2f(h));
    const long o = ob + (long)(n0 + ty + k * 8) * 512 + c0 + tx;
    X0[o] = h; X1[o] = m_;
  }
}

// V planes [n][c] -> [c][n]; xcT planes -> xc_cn bf16 [c][n] (h+m summed)
__global__ __launch_bounds__(256) void transpose_vxc(
    const unsigned short* __restrict__ VTh, const unsigned short* __restrict__ VTm,
    const unsigned short* __restrict__ xcTh, const unsigned short* __restrict__ xcTm,
    unsigned short* __restrict__ Vh, unsigned short* __restrict__ Vm,
    unsigned short* __restrict__ xccn)
{
  __shared__ unsigned short th[32][33], tm[32][33], tc[32][33];
  const int bz = blockIdx.z;
  const int n0 = blockIdx.x * 32, c0 = blockIdx.y * 32;
  const int tx = threadIdx.x & 31, ty = threadIdx.x >> 5;
  const long ib = (long)bz * 819200L;
#pragma unroll
  for (int k = 0; k < 4; k++) {
    const int rr = ty + k * 8;
    const long o = ib + (long)(n0 + rr) * 512 + c0 + tx;
    th[rr][tx] = VTh[o];
    tm[rr][tx] = VTm[o];
    tc[rr][tx] = f2bf(bf2f(xcTh[o]) + bf2f(xcTm[o]));
  }
  __syncthreads();
#pragma unroll
  for (int k = 0; k < 4; k++) {
    const int rr = ty + k * 8;
    const long o = ib + (long)(c0 + rr) * 1600 + n0 + tx;
    Vh[o] = th[tx][rr];
    Vm[o] = tm[tx][rr];
    xccn[o] = tc[tx][rr];
  }
}

__global__ __launch_bounds__(256) void split2_mat(
    const float* __restrict__ W, unsigned short* __restrict__ H,
    unsigned short* __restrict__ Mp, int n)
{
  const int i = blockIdx.x * 256 + threadIdx.x;
  if (i < n) {
    const float v = W[i];
    const unsigned short h = f2bf(v);
    H[i] = h; Mp[i] = f2bf(v - bf2f(h));
  }
}

// W' = W2 @ W1 (512^3, fp32 vector), split-written into 2 planes at row offset
__global__ __launch_bounds__(256) void combine_gemm(
    const float* __restrict__ A, const float* __restrict__ B,
    unsigned short* __restrict__ H, unsigned short* __restrict__ Mp, int rowoff)
{
  __shared__ float As[16][68];
  __shared__ float Bs[16][68];
  const int tid = threadIdx.x;
  const int m0 = blockIdx.y * 64, n0 = blockIdx.x * 64;
  const int tx = tid & 15, ty = tid >> 4;
  float acc[4][4];
#pragma unroll
  for (int i = 0; i < 4; i++)
#pragma unroll
    for (int j = 0; j < 4; j++) acc[i][j] = 0.f;
  for (int k0 = 0; k0 < 512; k0 += 16) {
    {
      const int cA = tid & 15, r0 = tid >> 4;
#pragma unroll
      for (int l = 0; l < 4; l++)
        As[cA][r0 + 16 * l] = A[(long)(m0 + r0 + 16 * l) * 512 + (k0 + cA)];
      const int c2 = tid & 63, r2 = tid >> 6;
#pragma unroll
      for (int l = 0; l < 4; l++)
        Bs[r2 + 4 * l][c2] = B[(long)(k0 + r2 + 4 * l) * 512 + (n0 + c2)];
    }
    __syncthreads();
#pragma unroll
    for (int kk = 0; kk < 16; kk++) {
      float a[4], b[4];
#pragma unroll
      for (int i = 0; i < 4; i++) a[i] = As[kk][ty * 4 + i];
#pragma unroll
      for (int j = 0; j < 4; j++) b[j] = Bs[kk][tx * 4 + j];
#pragma unroll
      for (int i = 0; i < 4; i++)
#pragma unroll
        for (int j = 0; j < 4; j++) acc[i][j] = fmaf(a[i], b[j], acc[i][j]);
    }
    __syncthreads();
  }
#pragma unroll
  for (int i = 0; i < 4; i++) {
    const int m = rowoff + m0 + ty * 4 + i;
#pragma unroll
    for (int j = 0; j < 4; j++) {
      const int n = n0 + tx * 4 + j;
      const float v = acc[i][j];
      const unsigned short h = f2bf(v);
      const long o = (long)m * 512 + n;
      H[o] = h; Mp[o] = f2bf(v - bf2f(h));
    }
  }
}

__global__ __launch_bounds__(256) void bias_combine(
    const float* __restrict__ W2, const float* __restrict__ b1,
    const float* __restrict__ b2, float* __restrict__ bout)
{
  const int o = blockIdx.x * 256 + threadIdx.x;
  if (o < 512) {
    float acc = b2[o];
    for (int t = 0; t < 512; t++) acc = fmaf(W2[(long)o * 512 + t], b1[t], acc);
    bout[o] = acc;
  }
}

#define NROW 1600
#define NB 1024
#define BOFF 3392

// softmax + rank mask; reads S row fp32, writes w = attn*mask as TWO bf16 planes
// in place: row n occupies bf16[0..1599]=h, bf16[1600..3199]=l of the old fp32 row.
__global__ __launch_bounds__(256) void rowproc(float* __restrict__ S)
{
  __shared__ float sm[NROW];
  __shared__ float wmask[NROW];
  __shared__ unsigned short gidx[NROW];
  __shared__ int hist[NB];
  __shared__ int Rb[NB];
  __shared__ int scA[256];
  __shared__ int scB[256];
  __shared__ float redf[256];

  const int tid = threadIdx.x;
  float* srow = S + (long)blockIdx.x * NROW;

  float lmax = -3.4e38f;
  for (int i = tid; i < NROW; i += 256) {
    const float v = srow[i];
    sm[i] = v;
    wmask[i] = 1.f;
    lmax = fmaxf(lmax, v);
  }
  redf[tid] = lmax;
#pragma unroll
  for (int j = 0; j < NB / 256; j++) hist[tid + 256 * j] = 0;
  __syncthreads();
#pragma unroll
  for (int s = 128; s > 0; s >>= 1) {
    if (tid < s) redf[tid] = fmaxf(redf[tid], redf[tid + s]);
    __syncthreads();
  }
  const float rmax = redf[0];
  __syncthreads();

  float lsum = 0.f;
  for (int i = tid; i < NROW; i += 256) {
    const float v = sm[i];
    lsum += __expf(v - rmax);
    if (v >= 0.f) {
      unsigned u = __float_as_uint(v) & 0x7fffffffu;
      int b = (int)(u >> 18) - BOFF;
      b = max(0, min(NB - 1, b));
      atomicAdd(&hist[b], 1);
    }
  }
  redf[tid] = lsum;
  __syncthreads();
#pragma unroll
  for (int s = 128; s > 0; s >>= 1) {
    if (tid < s) redf[tid] += redf[tid + s];
    __syncthreads();
  }
  const float Z = redf[0];

  const int h0 = hist[4 * tid], h1 = hist[4 * tid + 1];
  const int h2 = hist[4 * tid + 2], h3 = hist[4 * tid + 3];
  const int local = h0 + h1 + h2 + h3;
  scA[tid] = local;
  __syncthreads();
  int* src = scA;
  int* dst = scB;
#pragma unroll
  for (int d = 1; d < 256; d <<= 1) {
    const int v = src[tid] + ((tid + d < 256) ? src[tid + d] : 0);
    dst[tid] = v;
    __syncthreads();
    int* tp = src; src = dst; dst = tp;
  }
  const int P = src[0];
  const int hi = src[tid] - local;
  Rb[4 * tid + 3] = hi;
  Rb[4 * tid + 2] = hi + h3;
  Rb[4 * tid + 1] = hi + h3 + h2;
  Rb[4 * tid + 0] = hi + h3 + h2 + h1;
  __syncthreads();

  for (int i = tid; i < NROW; i += 256) {
    const float v = sm[i];
    if (v >= 0.f) {
      unsigned u = __float_as_uint(v) & 0x7fffffffu;
      int b = (int)(u >> 18) - BOFF;
      b = max(0, min(NB - 1, b));
      gidx[atomicAdd(&Rb[b], 1)] = (unsigned short)i;
    }
  }
  __syncthreads();

  for (int p = tid; p < P; p += 256) {
    const int ip = gidx[p];
    const float vp = sm[ip];
    unsigned u = __float_as_uint(vp) & 0x7fffffffu;
    int b = (int)(u >> 18) - BOFF;
    b = max(0, min(NB - 1, b));
    const int end = Rb[b];
    const int start = end - hist[b];
    int cnt = 0;
    for (int qq = start; qq < end; qq++) {
      const int iq = gidx[qq];
      const float vq = sm[iq];
      cnt += (int)((vq > vp) || ((vq == vp) && (iq < ip)));
    }
    const float r1 = (float)(start + cnt + 1);
    wmask[ip] = r1 * r1 * r1;
  }
  __syncthreads();

  const float invZ = 1.f / Z;
  unsigned short* wrow = (unsigned short*)srow;
  for (int i = tid; i < NROW; i += 256) {
    const float val = __expf(sm[i] - rmax) * invZ * wmask[i];
    const unsigned short h = f2bf(val);
    wrow[i] = h;
    wrow[NROW + i] = f2bf(val - bf2f(h));
  }
}

extern "C" void kernel_launch(void* const* d_in, const int* in_sizes, int n_in,
                              void* d_out, int out_size, void* d_ws, size_t ws_size,
                              hipStream_t stream)
{
  const float scale = 0.04419417382415922f;  // 1/sqrt(512)
  const long sCN = 819200L;                  // 512*1600
  const long sNN = 2560000L;                 // 1600*1600
  const long ePlane = 8L * sCN;              // elems per bf16 plane (batched)

  const float* x   = (const float*)d_in[0];
  const float* Wc  = (const float*)d_in[1];
  const float* bc  = (const float*)d_in[2];
  const float* Wq1 = (const float*)d_in[3];
  const float* bq1 = (const float*)d_in[4];
  const float* Wq2 = (const float*)d_in[5];
  const float* bq2 = (const float*)d_in[6];
  const float* Wk1 = (const float*)d_in[7];
  const float* bk1 = (const float*)d_in[8];
  const float* Wk2 = (const float*)d_in[9];
  const float* bk2 = (const float*)d_in[10];
  const float* Wv1 = (const float*)d_in[11];
  const float* bv1 = (const float*)d_in[12];
  const float* Wv2 = (const float*)d_in[13];
  const float* bv2 = (const float*)d_in[14];
  float* out = (float*)d_out;

  char* p = (char*)d_ws;
  auto carve = [&](size_t bytes) { char* r = p; p += (bytes + 255) & ~255UL; return r; };

  float* S = (float*)carve(8L * sNN * 4);  // S fp32; hosts xT planes early, w planes late
  unsigned short* Xh = (unsigned short*)S;
  unsigned short* Xm = Xh + ePlane;
  unsigned short* xcTh = (unsigned short*)carve(ePlane * 2);
  unsigned short* xcTm = (unsigned short*)carve(ePlane * 2);
  unsigned short* QTh = (unsigned short*)carve(ePlane * 2);
  unsigned short* QTm = (unsigned short*)carve(ePlane * 2);
  unsigned short* KTh = (unsigned short*)carve(ePlane * 2);
  unsigned short* KTm = (unsigned short*)carve(ePlane * 2);
  unsigned short* VTh = (unsigned short*)carve(ePlane * 2);
  unsigned short* VTm = (unsigned short*)carve(ePlane * 2);
  unsigned short* Vh = (unsigned short*)carve(ePlane * 2);
  unsigned short* Vm = (unsigned short*)carve(ePlane * 2);
  unsigned short* xc_cn = (unsigned short*)carve(ePlane * 2);
  unsigned short* Wch = (unsigned short*)carve(512L * 512 * 2);
  unsigned short* Wcm = (unsigned short*)carve(512L * 512 * 2);
  unsigned short* Wh = (unsigned short*)carve(1536L * 512 * 2);
  unsigned short* Wm = (unsigned short*)carve(1536L * 512 * 2);
  float* bqkv = (float*)carve(1536L * 4);

  // prep: x transpose+split, Wc split, combined weights/biases
  transpose_split_x<<<dim3(50, 16, 8), 256, 0, stream>>>(x, Xh, Xm);
  split2_mat<<<dim3(1024), 256, 0, stream>>>(Wc, Wch, Wcm, 512 * 512);
  combine_gemm<<<dim3(8, 8), 256, 0, stream>>>(Wq2, Wq1, Wh, Wm, 0);
  combine_gemm<<<dim3(8, 8), 256, 0, stream>>>(Wk2, Wk1, Wh, Wm, 512);
  combine_gemm<<<dim3(8, 8), 256, 0, stream>>>(Wv2, Wv1, Wh, Wm, 1024);
  bias_combine<<<dim3(2), 256, 0, stream>>>(Wq2, bq1, bq2, bqkv);
  bias_combine<<<dim3(2), 256, 0, stream>>>(Wk2, bk1, bk2, bqkv + 512);
  bias_combine<<<dim3(2), 256, 0, stream>>>(Wv2, bv1, bv2, bqkv + 1024);

  // xc = relu(xT . Wc^T + bc): [1600][512] -> xcT 2 planes
  mfma_gemm<0><<<dim3(4 * 13 * 8), 256, 0, stream>>>(
      Xh, Xm, Wch, Wcm, 4, 13, 1600, 512, 512, 512, 512, sCN, 0L, bc, 1.f,
      nullptr, 0L, xcTh, xcTm, sCN, nullptr, nullptr, 0L, nullptr, nullptr, 0L,
      nullptr, 0L);

  // fused QKV: [1600][1536]; Q,K,V all stored [n][c] 2-plane
  mfma_gemm<1><<<dim3(12 * 13 * 8), 256, 0, stream>>>(
      xcTh, xcTm, Wh, Wm, 12, 13, 1600, 1536, 512, 512, 512, sCN, 0L, bqkv, 1.f,
      nullptr, 0L, QTh, QTm, sCN, KTh, KTm, sCN, VTh, VTm, sCN, nullptr, 0L);

  // V -> [c][n] planes; xc residual -> bf16 [c][n]  (coalesced transposes)
  transpose_vxc<<<dim3(50, 16, 8), 256, 0, stream>>>(
      VTh, VTm, xcTh, xcTm, Vh, Vm, xc_cn);

  // S = scale * QT . KT^T : [1600][1600] fp32
  mfma_gemm<2><<<dim3(13 * 13 * 8), 256, 0, stream>>>(
      QTh, QTm, KTh, KTm, 13, 13, 1600, 1600, 512, 512, 512, sCN, sCN, nullptr, scale,
      S, sNN, nullptr, nullptr, 0L, nullptr, nullptr, 0L, nullptr, nullptr, 0L,
      nullptr, 0L);

  // softmax + rank mask; writes w h/l planes in place over S
  rowproc<<<dim3(12800), 256, 0, stream>>>(S);

  // out = V . w^T + xc : [512][1600] fp32 -> d_out
  mfma_gemm<3><<<dim3(13 * 4 * 8), 256, 0, stream>>>(
      Vh, Vm, (unsigned short*)S, (unsigned short*)S + 1600,
      13, 4, 512, 1600, 1600, 1600, 3200, sCN, 2L * sNN, nullptr, 1.f,
      out, sCN, nullptr, nullptr, 0L, nullptr, nullptr, 0L, nullptr, nullptr, 0L,
      xc_cn, sCN);
}

// Round 8
// 508.824 us; speedup vs baseline: 1.6473x; 1.2049x over previous
//
#include <hip/hip_runtime.h>
#include <math.h>

typedef short short8 __attribute__((ext_vector_type(8)));
typedef float f32x16 __attribute__((ext_vector_type(16)));

__device__ __forceinline__ unsigned short f2bf(float f) {
  unsigned u = __float_as_uint(f);
  unsigned r = u + 0x7fffu + ((u >> 16) & 1u);
  return (unsigned short)(r >> 16);
}
__device__ __forceinline__ float bf2f(unsigned short s) {
  return __uint_as_float(((unsigned)s) << 16);
}
__device__ __forceinline__ void gload_lds16(const void* g, void* l) {
  __builtin_amdgcn_global_load_lds(
      (const __attribute__((address_space(1))) unsigned int*)g,
      (__attribute__((address_space(3))) unsigned int*)l, 16, 0, 0);
}

#define TM 128
#define TN 128
#define GH 7  // y-tiles grouped per rasterization column (L2 locality)

// NT MFMA GEMM, 2-plane split (v ~= h + m), 3 products: hh + hm + mh.
// A [M][K] (ld=ldA), B [N][K] (ld=ldB). TK=32, SINGLE-buffer LDS (32 KB ->
// 4-5 blocks/CU; implicit cross-block overlap hides the vmcnt drain).
// 1D grid = GX*GY*GZ blocks (divisible by 8), XCD-chunked + grouped raster.
// MODE: 0=XC 1=QKV 2=S 3=OUT
template<int MODE>
__global__ __launch_bounds__(256, 4) void mfma_gemm(
    const unsigned short* __restrict__ A0, const unsigned short* __restrict__ A1,
    const unsigned short* __restrict__ B0, const unsigned short* __restrict__ B1,
    int GX, int GY,
    int M, int N, int K, int ldA, int ldB, long sA, long sB,
    const float* __restrict__ bias, float alpha,
    float* __restrict__ outF, long sOutF,
    unsigned short* __restrict__ P0, unsigned short* __restrict__ P1, long sP,
    unsigned short* __restrict__ R0, unsigned short* __restrict__ R1, long sR,
    unsigned short* __restrict__ V0, unsigned short* __restrict__ V1, long sV,
    const unsigned short* __restrict__ xcn, long sXcn)
{
  // [plane][128 rows x 32 k] ; 2*8KB*2 = 32 KB total
  __shared__ __align__(16) unsigned short As[2][128 * 32];
  __shared__ __align__(16) unsigned short Bs[2][128 * 32];

  const int tid = threadIdx.x;

  // ---- XCD-chunked bijective remap (total % 8 == 0) + grouped raster decode
  const int total = GX * GY * ((int)gridDim.x / (GX * GY));
  const int q = total >> 3;
  const int wg = blockIdx.x;
  const int c = (wg & 7) * q + (wg >> 3);
  const int pb = GX * GY;
  const int bz = c / pb;
  int r = c - bz * pb;
  const int gy = r / (GH * GX);
  int rr = r - gy * (GH * GX);
  const int hh = min(GH, GY - gy * GH);
  const int xt = rr / hh;
  const int yt = gy * GH + (rr - xt * hh);

  const int m0 = yt * TM, n0 = xt * TN;
  const int lane = tid & 63, w = tid >> 6;
  const int wm = w >> 1, wn = w & 1;
  const int g = lane >> 5, lr = lane & 31;

  // staging: issue i covers rows i*64 + (tid>>2), 16B slot tid&3; source
  // pre-swizzled so LDS slot s of row r holds k-chunk s ^ ((r>>1)&3)
  const int str = tid >> 2, sts = tid & 3;
  long aoff[2], boff[2];
#pragma unroll
  for (int i = 0; i < 2; i++) {
    const int rw = i * 64 + str;
    const int swc = (sts ^ ((rw >> 1) & 3)) * 8;
    aoff[i] = (long)min(m0 + rw, M - 1) * ldA + swc;
    boff[i] = (long)min(n0 + rw, N - 1) * ldB + swc;
  }
  const unsigned short* Ap[2] = {A0 + bz * sA, A1 + bz * sA};
  const unsigned short* Bp[2] = {B0 + bz * sB, B1 + bz * sB};

  f32x16 acc[2][2];
#pragma unroll
  for (int i = 0; i < 2; i++)
#pragma unroll
    for (int j = 0; j < 2; j++)
#pragma unroll
      for (int e = 0; e < 16; e++) acc[i][j][e] = 0.f;

  const int NT = K >> 5;

  for (int kt = 0; kt < NT; kt++) {
    const long k0 = (long)kt << 5;
    if (kt) __syncthreads();  // previous compute done before overwrite
#pragma unroll
    for (int p = 0; p < 2; p++)
#pragma unroll
      for (int i = 0; i < 2; i++) {
        gload_lds16(Ap[p] + aoff[i] + k0, (char*)&As[p][0] + i * 4096 + tid * 16);
        gload_lds16(Bp[p] + boff[i] + k0, (char*)&Bs[p][0] + i * 4096 + tid * 16);
      }
    __syncthreads();  // drain staging; other resident blocks compute meanwhile

#pragma unroll
    for (int kk = 0; kk < 2; kk++) {
      short8 af[2][2], bf[2][2];
#pragma unroll
      for (int i = 0; i < 2; i++) {
        const int rowa = wm * 64 + i * 32 + lr;
        const int sla = ((kk * 2 + g) ^ ((rowa >> 1) & 3)) * 8;
#pragma unroll
        for (int p = 0; p < 2; p++)
          af[i][p] = *(const short8*)&As[p][rowa * 32 + sla];
        const int rowb = wn * 64 + i * 32 + lr;
        const int slb = ((kk * 2 + g) ^ ((rowb >> 1) & 3)) * 8;
#pragma unroll
        for (int p = 0; p < 2; p++)
          bf[i][p] = *(const short8*)&Bs[p][rowb * 32 + slb];
      }
      __builtin_amdgcn_s_setprio(1);
#pragma unroll
      for (int i = 0; i < 2; i++)
#pragma unroll
        for (int j = 0; j < 2; j++) {
          acc[i][j] = __builtin_amdgcn_mfma_f32_32x32x16_bf16(af[i][0], bf[j][0], acc[i][j], 0, 0, 0);
          acc[i][j] = __builtin_amdgcn_mfma_f32_32x32x16_bf16(af[i][0], bf[j][1], acc[i][j], 0, 0, 0);
          acc[i][j] = __builtin_amdgcn_mfma_f32_32x32x16_bf16(af[i][1], bf[j][0], acc[i][j], 0, 0, 0);
        }
      __builtin_amdgcn_s_setprio(0);
    }
  }

  // epilogue: row = m0+wm*64+i*32 + rq*8 + g*4 + t ; col = n0+wn*64+j*32+lr
#pragma unroll
  for (int i = 0; i < 2; i++)
#pragma unroll
    for (int j = 0; j < 2; j++) {
      const int cb = n0 + wn * 64 + j * 32;
      const int col = cb + lr;
#pragma unroll
      for (int rq = 0; rq < 4; rq++)
#pragma unroll
        for (int t = 0; t < 4; t++) {
          const int reg = rq * 4 + t;
          const int row = m0 + wm * 64 + i * 32 + rq * 8 + g * 4 + t;
          float v = acc[i][j][reg];
          if (MODE == 0) {  // XC: relu, 2-plane xcT [n][c]
            if (row < M) {
              v += bias[col];
              v = fmaxf(v, 0.f);
              const unsigned short h = f2bf(v);
              const unsigned short m_ = f2bf(v - bf2f(h));
              const long o = bz * sP + (long)row * 512 + col;
              P0[o] = h; P1[o] = m_;
            }
          } else if (MODE == 1) {  // QKV: all segments [n][c] coalesced
            if (row < M) {
              v += bias[col];
              const unsigned short h = f2bf(v);
              const unsigned short m_ = f2bf(v - bf2f(h));
              const int sc = col & 511;
              if (cb < 512) {
                const long o = bz * sP + (long)row * 512 + sc;
                P0[o] = h; P1[o] = m_;
              } else if (cb < 1024) {
                const long o = bz * sR + (long)row * 512 + sc;
                R0[o] = h; R1[o] = m_;
              } else {
                const long o = bz * sV + (long)row * 512 + sc;
                V0[o] = h; V1[o] = m_;
              }
            }
          } else if (MODE == 2) {  // S
            if (row < M && col < N)
              outF[bz * sOutF + (long)row * 1600 + col] = v * alpha;
          } else {  // OUT: += residual (xc_cn bf16, coalesced)
            if (col < N) {
              v += bf2f(xcn[bz * sXcn + (long)row * 1600 + col]);
              outF[bz * sOutF + (long)row * 1600 + col] = v;
            }
          }
        }
    }
}

// x [B][C][N] f32 -> xT planes [B][N][C] bf16 h/m
__global__ __launch_bounds__(256) void transpose_split_x(
    const float* __restrict__ x, unsigned short* __restrict__ X0,
    unsigned short* __restrict__ X1)
{
  __shared__ float t[32][33];
  const int bz = blockIdx.z;
  const int n0 = blockIdx.x * 32, c0 = blockIdx.y * 32;
  const int tx = threadIdx.x & 31, ty = threadIdx.x >> 5;
  const float* xb = x + (long)bz * 512 * 1600;
#pragma unroll
  for (int k = 0; k < 4; k++)
    t[ty + k * 8][tx] = xb[(long)(c0 + ty + k * 8) * 1600 + n0 + tx];
  __syncthreads();
  const long ob = (long)bz * 1600 * 512;
#pragma unroll
  for (int k = 0; k < 4; k++) {
    const float v = t[tx][ty + k * 8];
    const unsigned short h = f2bf(v);
    const unsigned short m_ = f2bf(v - bf2f(h));
    const long o = ob + (long)(n0 + ty + k * 8) * 512 + c0 + tx;
    X0[o] = h; X1[o] = m_;
  }
}

// V planes [n][c] -> [c][n]; xcT planes -> xc_cn bf16 [c][n] (h+m summed)
__global__ __launch_bounds__(256) void transpose_vxc(
    const unsigned short* __restrict__ VTh, const unsigned short* __restrict__ VTm,
    const unsigned short* __restrict__ xcTh, const unsigned short* __restrict__ xcTm,
    unsigned short* __restrict__ Vh, unsigned short* __restrict__ Vm,
    unsigned short* __restrict__ xccn)
{
  __shared__ unsigned short th[32][33], tm[32][33], tc[32][33];
  const int bz = blockIdx.z;
  const int n0 = blockIdx.x * 32, c0 = blockIdx.y * 32;
  const int tx = threadIdx.x & 31, ty = threadIdx.x >> 5;
  const long ib = (long)bz * 819200L;
#pragma unroll
  for (int k = 0; k < 4; k++) {
    const int rr = ty + k * 8;
    const long o = ib + (long)(n0 + rr) * 512 + c0 + tx;
    th[rr][tx] = VTh[o];
    tm[rr][tx] = VTm[o];
    tc[rr][tx] = f2bf(bf2f(xcTh[o]) + bf2f(xcTm[o]));
  }
  __syncthreads();
#pragma unroll
  for (int k = 0; k < 4; k++) {
    const int rr = ty + k * 8;
    const long o = ib + (long)(c0 + rr) * 1600 + n0 + tx;
    Vh[o] = th[tx][rr];
    Vm[o] = tm[tx][rr];
    xccn[o] = tc[tx][rr];
  }
}

__global__ __launch_bounds__(256) void split2_mat(
    const float* __restrict__ W, unsigned short* __restrict__ H,
    unsigned short* __restrict__ Mp, int n)
{
  const int i = blockIdx.x * 256 + threadIdx.x;
  if (i < n) {
    const float v = W[i];
    const unsigned short h = f2bf(v);
    H[i] = h; Mp[i] = f2bf(v - bf2f(h));
  }
}

// batched: bz selects (A,B) pair; W' = A @ B, planes written at rowoff = bz*512
__global__ __launch_bounds__(256) void combine_gemm3(
    const float* __restrict__ Aq, const float* __restrict__ Bq,
    const float* __restrict__ Ak, const float* __restrict__ Bk,
    const float* __restrict__ Av, const float* __restrict__ Bv,
    unsigned short* __restrict__ H, unsigned short* __restrict__ Mp)
{
  __shared__ float As[16][68];
  __shared__ float Bs[16][68];
  const int tid = threadIdx.x;
  const int bz = blockIdx.z;
  const float* A = (bz == 0) ? Aq : (bz == 1) ? Ak : Av;
  const float* B = (bz == 0) ? Bq : (bz == 1) ? Bk : Bv;
  const int rowoff = bz * 512;
  const int m0 = blockIdx.y * 64, n0 = blockIdx.x * 64;
  const int tx = tid & 15, ty = tid >> 4;
  float acc[4][4];
#pragma unroll
  for (int i = 0; i < 4; i++)
#pragma unroll
    for (int j = 0; j < 4; j++) acc[i][j] = 0.f;
  for (int k0 = 0; k0 < 512; k0 += 16) {
    {
      const int cA = tid & 15, r0 = tid >> 4;
#pragma unroll
      for (int l = 0; l < 4; l++)
        As[cA][r0 + 16 * l] = A[(long)(m0 + r0 + 16 * l) * 512 + (k0 + cA)];
      const int c2 = tid & 63, r2 = tid >> 6;
#pragma unroll
      for (int l = 0; l < 4; l++)
        Bs[r2 + 4 * l][c2] = B[(long)(k0 + r2 + 4 * l) * 512 + (n0 + c2)];
    }
    __syncthreads();
#pragma unroll
    for (int kk = 0; kk < 16; kk++) {
      float a[4], b[4];
#pragma unroll
      for (int i = 0; i < 4; i++) a[i] = As[kk][ty * 4 + i];
#pragma unroll
      for (int j = 0; j < 4; j++) b[j] = Bs[kk][tx * 4 + j];
#pragma unroll
      for (int i = 0; i < 4; i++)
#pragma unroll
        for (int j = 0; j < 4; j++) acc[i][j] = fmaf(a[i], b[j], acc[i][j]);
    }
    __syncthreads();
  }
#pragma unroll
  for (int i = 0; i < 4; i++) {
    const int m = rowoff + m0 + ty * 4 + i;
#pragma unroll
    for (int j = 0; j < 4; j++) {
      const int n = n0 + tx * 4 + j;
      const float v = acc[i][j];
      const unsigned short h = f2bf(v);
      const long o = (long)m * 512 + n;
      H[o] = h; Mp[o] = f2bf(v - bf2f(h));
    }
  }
}

// batched: bz selects (W2,b1,b2); bout offset bz*512
__global__ __launch_bounds__(256) void bias_combine3(
    const float* __restrict__ W2q, const float* __restrict__ b1q, const float* __restrict__ b2q,
    const float* __restrict__ W2k, const float* __restrict__ b1k, const float* __restrict__ b2k,
    const float* __restrict__ W2v, const float* __restrict__ b1v, const float* __restrict__ b2v,
    float* __restrict__ bout)
{
  const int bz = blockIdx.z;
  const float* W2 = (bz == 0) ? W2q : (bz == 1) ? W2k : W2v;
  const float* b1 = (bz == 0) ? b1q : (bz == 1) ? b1k : b1v;
  const float* b2 = (bz == 0) ? b2q : (bz == 1) ? b2k : b2v;
  const int o = blockIdx.x * 256 + threadIdx.x;
  if (o < 512) {
    float acc = b2[o];
    for (int t = 0; t < 512; t++) acc = fmaf(W2[(long)o * 512 + t], b1[t], acc);
    bout[bz * 512 + o] = acc;
  }
}

#define NROW 1600
#define NB 512
#define BOFF2 1696  // (exp=106)<<4 : 16 bins/octave covering 2^-21..2^11

// softmax + rank mask; reads S row fp32, writes w = attn*mask as TWO bf16 planes
// in place (row n: bf16[0..1599]=h, bf16[1600..3199]=l of the old fp32 row).
// v3: shfl reductions + shfl suffix-scan -> 6 barriers total, 20 KB LDS.
__global__ __launch_bounds__(256) void rowproc(float* __restrict__ S)
{
  __shared__ float sm[NROW];
  __shared__ float wmask[NROW];
  __shared__ unsigned short gidx[NROW];
  __shared__ int hist[NB];
  __shared__ int Rb[NB];
  __shared__ float redf[8];
  __shared__ int wtot[4];

  const int tid = threadIdx.x;
  const int lane = tid & 63, wid = tid >> 6;
  float* srow = S + (long)blockIdx.x * NROW;

  // ---- load + per-wave max; zero hist
  float lmax = -3.4e38f;
  for (int i = tid; i < NROW; i += 256) {
    const float v = srow[i];
    sm[i] = v;
    wmask[i] = 1.f;
    lmax = fmaxf(lmax, v);
  }
  for (int j = tid; j < NB; j += 256) hist[j] = 0;
#pragma unroll
  for (int d = 32; d; d >>= 1) lmax = fmaxf(lmax, __shfl_xor(lmax, d, 64));
  if (lane == 0) redf[wid] = lmax;
  __syncthreads();  // B1
  const float rmax = fmaxf(fmaxf(redf[0], redf[1]), fmaxf(redf[2], redf[3]));

  // ---- expsum + histogram of positives
  float lsum = 0.f;
  for (int i = tid; i < NROW; i += 256) {
    const float v = sm[i];
    lsum += __expf(v - rmax);
    if (v >= 0.f) {
      unsigned u = __float_as_uint(v) & 0x7fffffffu;
      int b = (int)(u >> 19) - BOFF2;
      b = max(0, min(NB - 1, b));
      atomicAdd(&hist[b], 1);
    }
  }
#pragma unroll
  for (int d = 32; d; d >>= 1) lsum += __shfl_xor(lsum, d, 64);
  if (lane == 0) redf[4 + wid] = lsum;
  __syncthreads();  // B2 (hist also complete)
  const float Z = redf[4] + redf[5] + redf[6] + redf[7];

  // ---- suffix scan: thread owns bins 2t,2t+1 (ascending); rank base of bin b
  // = #elements in bins > b
  const int h0 = hist[2 * tid], h1 = hist[2 * tid + 1];
  const int loc = h0 + h1;
  int suf = loc;
#pragma unroll
  for (int d = 1; d < 64; d <<= 1) {
    const int o = __shfl_down(suf, d, 64);
    if (lane + d < 64) suf += o;
  }
  if (lane == 0) wtot[wid] = suf;  // wave total (suffix over whole wave)
  __syncthreads();  // B3
  int above = 0;
#pragma unroll
  for (int w2 = 0; w2 < 4; w2++)
    if (w2 > wid) above += wtot[w2];
  const int P = wtot[0] + wtot[1] + wtot[2] + wtot[3];
  const int hiAll = (suf - loc) + above;  // elements in bins above this thread's
  Rb[2 * tid + 1] = hiAll;
  Rb[2 * tid] = hiAll + h1;
  __syncthreads();  // B4

  // ---- scatter positives into bin groups
  for (int i = tid; i < NROW; i += 256) {
    const float v = sm[i];
    if (v >= 0.f) {
      unsigned u = __float_as_uint(v) & 0x7fffffffu;
      int b = (int)(u >> 19) - BOFF2;
      b = max(0, min(NB - 1, b));
      gidx[atomicAdd(&Rb[b], 1)] = (unsigned short)i;
    }
  }
  __syncthreads();  // B5
  // now Rb[b] = group end; start = Rb[b]-hist[b] = rank base

  // ---- within-bucket exact stable descending rank
  for (int p = tid; p < P; p += 256) {
    const int ip = gidx[p];
    const float vp = sm[ip];
    unsigned u = __float_as_uint(vp) & 0x7fffffffu;
    int b = (int)(u >> 19) - BOFF2;
    b = max(0, min(NB - 1, b));
    const int end = Rb[b];
    const int start = end - hist[b];
    int cnt = 0;
    for (int qq = start; qq < end; qq++) {
      const int iq = gidx[qq];
      const float vq = sm[iq];
      cnt += (int)((vq > vp) || ((vq == vp) && (iq < ip)));
    }
    const float r1 = (float)(start + cnt + 1);
    wmask[ip] = r1 * r1 * r1;
  }
  __syncthreads();  // B6

  // ---- write attn * mask as h/l bf16 planes
  const float invZ = 1.f / Z;
  unsigned short* wrow = (unsigned short*)srow;
  for (int i = tid; i < NROW; i += 256) {
    const float val = __expf(sm[i] - rmax) * invZ * wmask[i];
    const unsigned short h = f2bf(val);
    wrow[i] = h;
    wrow[NROW + i] = f2bf(val - bf2f(h));
  }
}

extern "C" void kernel_launch(void* const* d_in, const int* in_sizes, int n_in,
                              void* d_out, int out_size, void* d_ws, size_t ws_size,
                              hipStream_t stream)
{
  const float scale = 0.04419417382415922f;  // 1/sqrt(512)
  const long sCN = 819200L;                  // 512*1600
  const long sNN = 2560000L;                 // 1600*1600
  const long ePlane = 8L * sCN;              // elems per bf16 plane (batched)

  const float* x   = (const float*)d_in[0];
  const float* Wc  = (const float*)d_in[1];
  const float* bc  = (const float*)d_in[2];
  const float* Wq1 = (const float*)d_in[3];
  const float* bq1 = (const float*)d_in[4];
  const float* Wq2 = (const float*)d_in[5];
  const float* bq2 = (const float*)d_in[6];
  const float* Wk1 = (const float*)d_in[7];
  const float* bk1 = (const float*)d_in[8];
  const float* Wk2 = (const float*)d_in[9];
  const float* bk2 = (const float*)d_in[10];
  const float* Wv1 = (const float*)d_in[11];
  const float* bv1 = (const float*)d_in[12];
  const float* Wv2 = (const float*)d_in[13];
  const float* bv2 = (const float*)d_in[14];
  float* out = (float*)d_out;

  char* p = (char*)d_ws;
  auto carve = [&](size_t bytes) { char* r = p; p += (bytes + 255) & ~255UL; return r; };

  float* S = (float*)carve(8L * sNN * 4);  // S fp32; hosts xT planes early, w planes late
  unsigned short* Xh = (unsigned short*)S;
  unsigned short* Xm = Xh + ePlane;
  unsigned short* xcTh = (unsigned short*)carve(ePlane * 2);
  unsigned short* xcTm = (unsigned short*)carve(ePlane * 2);
  unsigned short* QTh = (unsigned short*)carve(ePlane * 2);
  unsigned short* QTm = (unsigned short*)carve(ePlane * 2);
  unsigned short* KTh = (unsigned short*)carve(ePlane * 2);
  unsigned short* KTm = (unsigned short*)carve(ePlane * 2);
  unsigned short* VTh = (unsigned short*)carve(ePlane * 2);
  unsigned short* VTm = (unsigned short*)carve(ePlane * 2);
  unsigned short* Vh = (unsigned short*)carve(ePlane * 2);
  unsigned short* Vm = (unsigned short*)carve(ePlane * 2);
  unsigned short* xc_cn = (unsigned short*)carve(ePlane * 2);
  unsigned short* Wch = (unsigned short*)carve(512L * 512 * 2);
  unsigned short* Wcm = (unsigned short*)carve(512L * 512 * 2);
  unsigned short* Wh = (unsigned short*)carve(1536L * 512 * 2);
  unsigned short* Wm = (unsigned short*)carve(1536L * 512 * 2);
  float* bqkv = (float*)carve(1536L * 4);

  // prep: x transpose+split, Wc split, combined weights/biases (batched)
  transpose_split_x<<<dim3(50, 16, 8), 256, 0, stream>>>(x, Xh, Xm);
  split2_mat<<<dim3(1024), 256, 0, stream>>>(Wc, Wch, Wcm, 512 * 512);
  combine_gemm3<<<dim3(8, 8, 3), 256, 0, stream>>>(Wq2, Wq1, Wk2, Wk1, Wv2, Wv1, Wh, Wm);
  bias_combine3<<<dim3(2, 1, 3), 256, 0, stream>>>(Wq2, bq1, bq2, Wk2, bk1, bk2,
                                                   Wv2, bv1, bv2, bqkv);

  // xc = relu(xT . Wc^T + bc): [1600][512] -> xcT 2 planes
  mfma_gemm<0><<<dim3(4 * 13 * 8), 256, 0, stream>>>(
      Xh, Xm, Wch, Wcm, 4, 13, 1600, 512, 512, 512, 512, sCN, 0L, bc, 1.f,
      nullptr, 0L, xcTh, xcTm, sCN, nullptr, nullptr, 0L, nullptr, nullptr, 0L,
      nullptr, 0L);

  // fused QKV: [1600][1536]; Q,K,V all stored [n][c] 2-plane
  mfma_gemm<1><<<dim3(12 * 13 * 8), 256, 0, stream>>>(
      xcTh, xcTm, Wh, Wm, 12, 13, 1600, 1536, 512, 512, 512, sCN, 0L, bqkv, 1.f,
      nullptr, 0L, QTh, QTm, sCN, KTh, KTm, sCN, VTh, VTm, sCN, nullptr, 0L);

  // V -> [c][n] planes; xc residual -> bf16 [c][n]  (coalesced transposes)
  transpose_vxc<<<dim3(50, 16, 8), 256, 0, stream>>>(
      VTh, VTm, xcTh, xcTm, Vh, Vm, xc_cn);

  // S = scale * QT . KT^T : [1600][1600] fp32
  mfma_gemm<2><<<dim3(13 * 13 * 8), 256, 0, stream>>>(
      QTh, QTm, KTh, KTm, 13, 13, 1600, 1600, 512, 512, 512, sCN, sCN, nullptr, scale,
      S, sNN, nullptr, nullptr, 0L, nullptr, nullptr, 0L, nullptr, nullptr, 0L,
      nullptr, 0L);

  // softmax + rank mask; writes w h/l planes in place over S
  rowproc<<<dim3(12800), 256, 0, stream>>>(S);

  // out = V . w^T + xc : [512][1600] fp32 -> d_out
  mfma_gemm<3><<<dim3(13 * 4 * 8), 256, 0, stream>>>(
      Vh, Vm, (unsigned short*)S, (unsigned short*)S + 1600,
      13, 4, 512, 1600, 1600, 1600, 3200, sCN, 2L * sNN, nullptr, 1.f,
      out, sCN, nullptr, nullptr, 0L, nullptr, nullptr, 0L, nullptr, nullptr, 0L,
      xc_cn, sCN);
}

// Round 9
// 443.487 us; speedup vs baseline: 1.8900x; 1.1473x over previous
//
#include <hip/hip_runtime.h>
#include <math.h>

typedef short short8 __attribute__((ext_vector_type(8)));
typedef float f32x16 __attribute__((ext_vector_type(16)));

__device__ __forceinline__ unsigned short f2bf(float f) {
  unsigned u = __float_as_uint(f);
  unsigned r = u + 0x7fffu + ((u >> 16) & 1u);
  return (unsigned short)(r >> 16);
}
__device__ __forceinline__ float bf2f(unsigned short s) {
  return __uint_as_float(((unsigned)s) << 16);
}
__device__ __forceinline__ void gload_lds16(const void* g, void* l) {
  __builtin_amdgcn_global_load_lds(
      (const __attribute__((address_space(1))) unsigned int*)g,
      (__attribute__((address_space(3))) unsigned int*)l, 16, 0, 0);
}

#define TM 128
#define TN 128
#define GH 7  // y-tiles grouped per rasterization column (L2 locality)

// NT MFMA GEMM. NPROD=3: 2-plane split (v~=h+m), products hh+hm+mh.
// NPROD=1: single bf16 plane, 1 product (for OUT: no sign decisions downstream).
// A [M][K] (ld=ldA), B [N][K] (ld=ldB). TK=32, SINGLE-buffer LDS;
// cross-block overlap hides the vmcnt drain (4+ blocks/CU).
// 1D grid = GX*GY*GZ blocks (divisible by 8), XCD-chunked + grouped raster.
// MODE: 0=XC 1=QKV 2=S 3=OUT
template<int MODE, int NPROD>
__global__ __launch_bounds__(256, 4) void mfma_gemm(
    const unsigned short* __restrict__ A0, const unsigned short* __restrict__ A1,
    const unsigned short* __restrict__ B0, const unsigned short* __restrict__ B1,
    int GX, int GY,
    int M, int N, int K, int ldA, int ldB, long sA, long sB,
    const float* __restrict__ bias, float alpha,
    float* __restrict__ outF, long sOutF,
    unsigned short* __restrict__ P0, unsigned short* __restrict__ P1, long sP,
    unsigned short* __restrict__ R0, unsigned short* __restrict__ R1, long sR,
    unsigned short* __restrict__ V0, long sV,
    const unsigned short* __restrict__ xcn, long sXcn)
{
  constexpr int NPL = (NPROD == 3) ? 2 : 1;
  // [plane][128 rows x 32 k] ; NPL*8KB*2 total
  __shared__ __align__(16) unsigned short As[NPL][128 * 32];
  __shared__ __align__(16) unsigned short Bs[NPL][128 * 32];

  const int tid = threadIdx.x;

  // ---- XCD-chunked bijective remap (total % 8 == 0) + grouped raster decode
  const int total = GX * GY * ((int)gridDim.x / (GX * GY));
  const int q = total >> 3;
  const int wg = blockIdx.x;
  const int c = (wg & 7) * q + (wg >> 3);
  const int pb = GX * GY;
  const int bz = c / pb;
  int r = c - bz * pb;
  const int gy = r / (GH * GX);
  int rr = r - gy * (GH * GX);
  const int hh = min(GH, GY - gy * GH);
  const int xt = rr / hh;
  const int yt = gy * GH + (rr - xt * hh);

  const int m0 = yt * TM, n0 = xt * TN;
  const int lane = tid & 63, w = tid >> 6;
  const int wm = w >> 1, wn = w & 1;
  const int g = lane >> 5, lr = lane & 31;

  // staging: issue i covers rows i*64 + (tid>>2), 16B slot tid&3; source
  // pre-swizzled so LDS slot s of row r holds k-chunk s ^ ((r>>1)&3)
  const int str = tid >> 2, sts = tid & 3;
  long aoff[2], boff[2];
#pragma unroll
  for (int i = 0; i < 2; i++) {
    const int rw = i * 64 + str;
    const int swc = (sts ^ ((rw >> 1) & 3)) * 8;
    aoff[i] = (long)min(m0 + rw, M - 1) * ldA + swc;
    boff[i] = (long)min(n0 + rw, N - 1) * ldB + swc;
  }
  const unsigned short* Ap[2];
  const unsigned short* Bp[2];
  Ap[0] = A0 + bz * sA;
  Bp[0] = B0 + bz * sB;
  Ap[1] = (NPL == 2) ? A1 + bz * sA : Ap[0];
  Bp[1] = (NPL == 2) ? B1 + bz * sB : Bp[0];

  f32x16 acc[2][2];
#pragma unroll
  for (int i = 0; i < 2; i++)
#pragma unroll
    for (int j = 0; j < 2; j++)
#pragma unroll
      for (int e = 0; e < 16; e++) acc[i][j][e] = 0.f;

  const int NT = K >> 5;

  for (int kt = 0; kt < NT; kt++) {
    const long k0 = (long)kt << 5;
    if (kt) __syncthreads();  // previous compute done before overwrite
#pragma unroll
    for (int p = 0; p < NPL; p++)
#pragma unroll
      for (int i = 0; i < 2; i++) {
        gload_lds16(Ap[p] + aoff[i] + k0, (char*)&As[p][0] + i * 4096 + tid * 16);
        gload_lds16(Bp[p] + boff[i] + k0, (char*)&Bs[p][0] + i * 4096 + tid * 16);
      }
    __syncthreads();  // drain staging; other resident blocks compute meanwhile

#pragma unroll
    for (int kk = 0; kk < 2; kk++) {
      short8 af[2][NPL], bf[2][NPL];
#pragma unroll
      for (int i = 0; i < 2; i++) {
        const int rowa = wm * 64 + i * 32 + lr;
        const int sla = ((kk * 2 + g) ^ ((rowa >> 1) & 3)) * 8;
#pragma unroll
        for (int p = 0; p < NPL; p++)
          af[i][p] = *(const short8*)&As[p][rowa * 32 + sla];
        const int rowb = wn * 64 + i * 32 + lr;
        const int slb = ((kk * 2 + g) ^ ((rowb >> 1) & 3)) * 8;
#pragma unroll
        for (int p = 0; p < NPL; p++)
          bf[i][p] = *(const short8*)&Bs[p][rowb * 32 + slb];
      }
      __builtin_amdgcn_s_setprio(1);
#pragma unroll
      for (int i = 0; i < 2; i++)
#pragma unroll
        for (int j = 0; j < 2; j++) {
          acc[i][j] = __builtin_amdgcn_mfma_f32_32x32x16_bf16(af[i][0], bf[j][0], acc[i][j], 0, 0, 0);
          if (NPROD == 3) {
            acc[i][j] = __builtin_amdgcn_mfma_f32_32x32x16_bf16(af[i][0], bf[j][1], acc[i][j], 0, 0, 0);
            acc[i][j] = __builtin_amdgcn_mfma_f32_32x32x16_bf16(af[i][1], bf[j][0], acc[i][j], 0, 0, 0);
          }
        }
      __builtin_amdgcn_s_setprio(0);
    }
  }

  // epilogue: row = m0+wm*64+i*32 + rq*8 + g*4 + t ; col = n0+wn*64+j*32+lr
#pragma unroll
  for (int i = 0; i < 2; i++)
#pragma unroll
    for (int j = 0; j < 2; j++) {
      const int cb = n0 + wn * 64 + j * 32;
      const int col = cb + lr;
#pragma unroll
      for (int rq = 0; rq < 4; rq++)
#pragma unroll
        for (int t = 0; t < 4; t++) {
          const int reg = rq * 4 + t;
          const int row = m0 + wm * 64 + i * 32 + rq * 8 + g * 4 + t;
          float v = acc[i][j][reg];
          if (MODE == 0) {  // XC: relu, 2-plane xcT [n][c]
            if (row < M) {
              v += bias[col];
              v = fmaxf(v, 0.f);
              const unsigned short h = f2bf(v);
              const unsigned short m_ = f2bf(v - bf2f(h));
              const long o = bz * sP + (long)row * 512 + col;
              P0[o] = h; P1[o] = m_;
            }
          } else if (MODE == 1) {  // QKV: [n][c] coalesced; V single-plane
            if (row < M) {
              v += bias[col];
              const unsigned short h = f2bf(v);
              const int sc = col & 511;
              if (cb < 512) {
                const unsigned short m_ = f2bf(v - bf2f(h));
                const long o = bz * sP + (long)row * 512 + sc;
                P0[o] = h; P1[o] = m_;
              } else if (cb < 1024) {
                const unsigned short m_ = f2bf(v - bf2f(h));
                const long o = bz * sR + (long)row * 512 + sc;
                R0[o] = h; R1[o] = m_;
              } else {
                V0[bz * sV + (long)row * 512 + sc] = h;
              }
            }
          } else if (MODE == 2) {  // S
            if (row < M && col < N)
              outF[bz * sOutF + (long)row * 1600 + col] = v * alpha;
          } else {  // OUT: += residual (xc_cn bf16, coalesced)
            if (col < N) {
              v += bf2f(xcn[bz * sXcn + (long)row * 1600 + col]);
              outF[bz * sOutF + (long)row * 1600 + col] = v;
            }
          }
        }
    }
}

// x [B][C][N] f32 -> xT planes [B][N][C] bf16 h/m
__global__ __launch_bounds__(256) void transpose_split_x(
    const float* __restrict__ x, unsigned short* __restrict__ X0,
    unsigned short* __restrict__ X1)
{
  __shared__ float t[32][33];
  const int bz = blockIdx.z;
  const int n0 = blockIdx.x * 32, c0 = blockIdx.y * 32;
  const int tx = threadIdx.x & 31, ty = threadIdx.x >> 5;
  const float* xb = x + (long)bz * 512 * 1600;
#pragma unroll
  for (int k = 0; k < 4; k++)
    t[ty + k * 8][tx] = xb[(long)(c0 + ty + k * 8) * 1600 + n0 + tx];
  __syncthreads();
  const long ob = (long)bz * 1600 * 512;
#pragma unroll
  for (int k = 0; k < 4; k++) {
    const float v = t[tx][ty + k * 8];
    const unsigned short h = f2bf(v);
    const unsigned short m_ = f2bf(v - bf2f(h));
    const long o = ob + (long)(n0 + ty + k * 8) * 512 + c0 + tx;
    X0[o] = h; X1[o] = m_;
  }
}

// V h-plane [n][c] -> [c][n]; xcT planes -> xc_cn bf16 [c][n] (h+m summed)
__global__ __launch_bounds__(256) void transpose_vxc(
    const unsigned short* __restrict__ VTh,
    const unsigned short* __restrict__ xcTh, const unsigned short* __restrict__ xcTm,
    unsigned short* __restrict__ Vh, unsigned short* __restrict__ xccn)
{
  __shared__ unsigned short th[32][33], tc[32][33];
  const int bz = blockIdx.z;
  const int n0 = blockIdx.x * 32, c0 = blockIdx.y * 32;
  const int tx = threadIdx.x & 31, ty = threadIdx.x >> 5;
  const long ib = (long)bz * 819200L;
#pragma unroll
  for (int k = 0; k < 4; k++) {
    const int rr = ty + k * 8;
    const long o = ib + (long)(n0 + rr) * 512 + c0 + tx;
    th[rr][tx] = VTh[o];
    tc[rr][tx] = f2bf(bf2f(xcTh[o]) + bf2f(xcTm[o]));
  }
  __syncthreads();
#pragma unroll
  for (int k = 0; k < 4; k++) {
    const int rr = ty + k * 8;
    const long o = ib + (long)(c0 + rr) * 1600 + n0 + tx;
    Vh[o] = th[tx][rr];
    xccn[o] = tc[tx][rr];
  }
}

__global__ __launch_bounds__(256) void split2_mat(
    const float* __restrict__ W, unsigned short* __restrict__ H,
    unsigned short* __restrict__ Mp, int n)
{
  const int i = blockIdx.x * 256 + threadIdx.x;
  if (i < n) {
    const float v = W[i];
    const unsigned short h = f2bf(v);
    H[i] = h; Mp[i] = f2bf(v - bf2f(h));
  }
}

// batched: bz selects (A,B) pair; W' = A @ B, planes written at rowoff = bz*512
__global__ __launch_bounds__(256) void combine_gemm3(
    const float* __restrict__ Aq, const float* __restrict__ Bq,
    const float* __restrict__ Ak, const float* __restrict__ Bk,
    const float* __restrict__ Av, const float* __restrict__ Bv,
    unsigned short* __restrict__ H, unsigned short* __restrict__ Mp)
{
  __shared__ float As[16][68];
  __shared__ float Bs[16][68];
  const int tid = threadIdx.x;
  const int bz = blockIdx.z;
  const float* A = (bz == 0) ? Aq : (bz == 1) ? Ak : Av;
  const float* B = (bz == 0) ? Bq : (bz == 1) ? Bk : Bv;
  const int rowoff = bz * 512;
  const int m0 = blockIdx.y * 64, n0 = blockIdx.x * 64;
  const int tx = tid & 15, ty = tid >> 4;
  float acc[4][4];
#pragma unroll
  for (int i = 0; i < 4; i++)
#pragma unroll
    for (int j = 0; j < 4; j++) acc[i][j] = 0.f;
  for (int k0 = 0; k0 < 512; k0 += 16) {
    {
      const int cA = tid & 15, r0 = tid >> 4;
#pragma unroll
      for (int l = 0; l < 4; l++)
        As[cA][r0 + 16 * l] = A[(long)(m0 + r0 + 16 * l) * 512 + (k0 + cA)];
      const int c2 = tid & 63, r2 = tid >> 6;
#pragma unroll
      for (int l = 0; l < 4; l++)
        Bs[r2 + 4 * l][c2] = B[(long)(k0 + r2 + 4 * l) * 512 + (n0 + c2)];
    }
    __syncthreads();
#pragma unroll
    for (int kk = 0; kk < 16; kk++) {
      float a[4], b[4];
#pragma unroll
      for (int i = 0; i < 4; i++) a[i] = As[kk][ty * 4 + i];
#pragma unroll
      for (int j = 0; j < 4; j++) b[j] = Bs[kk][tx * 4 + j];
#pragma unroll
      for (int i = 0; i < 4; i++)
#pragma unroll
        for (int j = 0; j < 4; j++) acc[i][j] = fmaf(a[i], b[j], acc[i][j]);
    }
    __syncthreads();
  }
#pragma unroll
  for (int i = 0; i < 4; i++) {
    const int m = rowoff + m0 + ty * 4 + i;
#pragma unroll
    for (int j = 0; j < 4; j++) {
      const int n = n0 + tx * 4 + j;
      const float v = acc[i][j];
      const unsigned short h = f2bf(v);
      const long o = (long)m * 512 + n;
      H[o] = h; Mp[o] = f2bf(v - bf2f(h));
    }
  }
}

// batched: bz selects (W2,b1,b2); bout offset bz*512
__global__ __launch_bounds__(256) void bias_combine3(
    const float* __restrict__ W2q, const float* __restrict__ b1q, const float* __restrict__ b2q,
    const float* __restrict__ W2k, const float* __restrict__ b1k, const float* __restrict__ b2k,
    const float* __restrict__ W2v, const float* __restrict__ b1v, const float* __restrict__ b2v,
    float* __restrict__ bout)
{
  const int bz = blockIdx.z;
  const float* W2 = (bz == 0) ? W2q : (bz == 1) ? W2k : W2v;
  const float* b1 = (bz == 0) ? b1q : (bz == 1) ? b1k : b1v;
  const float* b2 = (bz == 0) ? b2q : (bz == 1) ? b2k : b2v;
  const int o = blockIdx.x * 256 + threadIdx.x;
  if (o < 512) {
    float acc = b2[o];
    for (int t = 0; t < 512; t++) acc = fmaf(W2[(long)o * 512 + t], b1[t], acc);
    bout[bz * 512 + o] = acc;
  }
}

#define NROW 1600
#define NB 1024
#define BOFF 3392  // (exp=106)<<5 : 32 bins/octave covering 2^-21..2^11

// softmax + rank mask; reads S row fp32, writes w = attn*mask as ONE bf16 plane
// in place (row n: bf16[0..1599] of the old fp32 row; rest unused).
// v4: shfl reductions/scan (6 barriers), 1024 bins (small refine groups), 24 KB LDS.
__global__ __launch_bounds__(256) void rowproc(float* __restrict__ S)
{
  __shared__ float sm[NROW];
  __shared__ float wmask[NROW];
  __shared__ unsigned short gidx[NROW];
  __shared__ int hist[NB];
  __shared__ int Rb[NB];
  __shared__ float redf[8];
  __shared__ int wtot[4];

  const int tid = threadIdx.x;
  const int lane = tid & 63, wid = tid >> 6;
  float* srow = S + (long)blockIdx.x * NROW;

  // ---- load + per-wave max; zero hist
  float lmax = -3.4e38f;
  for (int i = tid; i < NROW; i += 256) {
    const float v = srow[i];
    sm[i] = v;
    wmask[i] = 1.f;
    lmax = fmaxf(lmax, v);
  }
#pragma unroll
  for (int j = 0; j < NB / 256; j++) hist[tid + 256 * j] = 0;
#pragma unroll
  for (int d = 32; d; d >>= 1) lmax = fmaxf(lmax, __shfl_xor(lmax, d, 64));
  if (lane == 0) redf[wid] = lmax;
  __syncthreads();  // B1
  const float rmax = fmaxf(fmaxf(redf[0], redf[1]), fmaxf(redf[2], redf[3]));

  // ---- expsum + histogram of positives
  float lsum = 0.f;
  for (int i = tid; i < NROW; i += 256) {
    const float v = sm[i];
    lsum += __expf(v - rmax);
    if (v >= 0.f) {
      unsigned u = __float_as_uint(v) & 0x7fffffffu;
      int b = (int)(u >> 18) - BOFF;
      b = max(0, min(NB - 1, b));
      atomicAdd(&hist[b], 1);
    }
  }
#pragma unroll
  for (int d = 32; d; d >>= 1) lsum += __shfl_xor(lsum, d, 64);
  if (lane == 0) redf[4 + wid] = lsum;
  __syncthreads();  // B2 (hist also complete)
  const float Z = redf[4] + redf[5] + redf[6] + redf[7];

  // ---- suffix scan: thread owns bins 4t..4t+3 (ascending); rank base of bin b
  // = #elements in bins > b
  const int h0 = hist[4 * tid], h1 = hist[4 * tid + 1];
  const int h2 = hist[4 * tid + 2], h3 = hist[4 * tid + 3];
  const int loc = h0 + h1 + h2 + h3;
  int suf = loc;
#pragma unroll
  for (int d = 1; d < 64; d <<= 1) {
    const int o = __shfl_down(suf, d, 64);
    if (lane + d < 64) suf += o;
  }
  if (lane == 0) wtot[wid] = suf;
  __syncthreads();  // B3
  int above = 0;
#pragma unroll
  for (int w2 = 0; w2 < 4; w2++)
    if (w2 > wid) above += wtot[w2];
  const int P = wtot[0] + wtot[1] + wtot[2] + wtot[3];
  const int hiAll = (suf - loc) + above;
  Rb[4 * tid + 3] = hiAll;
  Rb[4 * tid + 2] = hiAll + h3;
  Rb[4 * tid + 1] = hiAll + h3 + h2;
  Rb[4 * tid + 0] = hiAll + h3 + h2 + h1;
  __syncthreads();  // B4

  // ---- scatter positives into bin groups
  for (int i = tid; i < NROW; i += 256) {
    const float v = sm[i];
    if (v >= 0.f) {
      unsigned u = __float_as_uint(v) & 0x7fffffffu;
      int b = (int)(u >> 18) - BOFF;
      b = max(0, min(NB - 1, b));
      gidx[atomicAdd(&Rb[b], 1)] = (unsigned short)i;
    }
  }
  __syncthreads();  // B5
  // now Rb[b] = group end; start = Rb[b]-hist[b] = rank base

  // ---- within-bucket exact stable descending rank
  for (int p = tid; p < P; p += 256) {
    const int ip = gidx[p];
    const float vp = sm[ip];
    unsigned u = __float_as_uint(vp) & 0x7fffffffu;
    int b = (int)(u >> 18) - BOFF;
    b = max(0, min(NB - 1, b));
    const int end = Rb[b];
    const int start = end - hist[b];
    int cnt = 0;
    for (int qq = start; qq < end; qq++) {
      const int iq = gidx[qq];
      const float vq = sm[iq];
      cnt += (int)((vq > vp) || ((vq == vp) && (iq < ip)));
    }
    const float r1 = (float)(start + cnt + 1);
    wmask[ip] = r1 * r1 * r1;
  }
  __syncthreads();  // B6

  // ---- write attn * mask as single bf16 plane
  const float invZ = 1.f / Z;
  unsigned short* wrow = (unsigned short*)srow;
  for (int i = tid; i < NROW; i += 256) {
    const float val = __expf(sm[i] - rmax) * invZ * wmask[i];
    wrow[i] = f2bf(val);
  }
}

extern "C" void kernel_launch(void* const* d_in, const int* in_sizes, int n_in,
                              void* d_out, int out_size, void* d_ws, size_t ws_size,
                              hipStream_t stream)
{
  const float scale = 0.04419417382415922f;  // 1/sqrt(512)
  const long sCN = 819200L;                  // 512*1600
  const long sNN = 2560000L;                 // 1600*1600
  const long ePlane = 8L * sCN;              // elems per bf16 plane (batched)

  const float* x   = (const float*)d_in[0];
  const float* Wc  = (const float*)d_in[1];
  const float* bc  = (const float*)d_in[2];
  const float* Wq1 = (const float*)d_in[3];
  const float* bq1 = (const float*)d_in[4];
  const float* Wq2 = (const float*)d_in[5];
  const float* bq2 = (const float*)d_in[6];
  const float* Wk1 = (const float*)d_in[7];
  const float* bk1 = (const float*)d_in[8];
  const float* Wk2 = (const float*)d_in[9];
  const float* bk2 = (const float*)d_in[10];
  const float* Wv1 = (const float*)d_in[11];
  const float* bv1 = (const float*)d_in[12];
  const float* Wv2 = (const float*)d_in[13];
  const float* bv2 = (const float*)d_in[14];
  float* out = (float*)d_out;

  char* p = (char*)d_ws;
  auto carve = [&](size_t bytes) { char* r = p; p += (bytes + 255) & ~255UL; return r; };

  float* S = (float*)carve(8L * sNN * 4);  // S fp32; hosts xT planes early, w plane late
  unsigned short* Xh = (unsigned short*)S;
  unsigned short* Xm = Xh + ePlane;
  unsigned short* xcTh = (unsigned short*)carve(ePlane * 2);
  unsigned short* xcTm = (unsigned short*)carve(ePlane * 2);
  unsigned short* QTh = (unsigned short*)carve(ePlane * 2);
  unsigned short* QTm = (unsigned short*)carve(ePlane * 2);
  unsigned short* KTh = (unsigned short*)carve(ePlane * 2);
  unsigned short* KTm = (unsigned short*)carve(ePlane * 2);
  unsigned short* VTh = (unsigned short*)carve(ePlane * 2);
  unsigned short* Vh = (unsigned short*)carve(ePlane * 2);
  unsigned short* xc_cn = (unsigned short*)carve(ePlane * 2);
  unsigned short* Wch = (unsigned short*)carve(512L * 512 * 2);
  unsigned short* Wcm = (unsigned short*)carve(512L * 512 * 2);
  unsigned short* Wh = (unsigned short*)carve(1536L * 512 * 2);
  unsigned short* Wm = (unsigned short*)carve(1536L * 512 * 2);
  float* bqkv = (float*)carve(1536L * 4);

  // prep: x transpose+split, Wc split, combined weights/biases (batched)
  transpose_split_x<<<dim3(50, 16, 8), 256, 0, stream>>>(x, Xh, Xm);
  split2_mat<<<dim3(1024), 256, 0, stream>>>(Wc, Wch, Wcm, 512 * 512);
  combine_gemm3<<<dim3(8, 8, 3), 256, 0, stream>>>(Wq2, Wq1, Wk2, Wk1, Wv2, Wv1, Wh, Wm);
  bias_combine3<<<dim3(2, 1, 3), 256, 0, stream>>>(Wq2, bq1, bq2, Wk2, bk1, bk2,
                                                   Wv2, bv1, bv2, bqkv);

  // xc = relu(xT . Wc^T + bc): [1600][512] -> xcT 2 planes
  mfma_gemm<0, 3><<<dim3(4 * 13 * 8), 256, 0, stream>>>(
      Xh, Xm, Wch, Wcm, 4, 13, 1600, 512, 512, 512, 512, sCN, 0L, bc, 1.f,
      nullptr, 0L, xcTh, xcTm, sCN, nullptr, nullptr, 0L, nullptr, 0L,
      nullptr, 0L);

  // fused QKV: [1600][1536]; Q,K 2-plane, V 1-plane, all [n][c]
  mfma_gemm<1, 3><<<dim3(12 * 13 * 8), 256, 0, stream>>>(
      xcTh, xcTm, Wh, Wm, 12, 13, 1600, 1536, 512, 512, 512, sCN, 0L, bqkv, 1.f,
      nullptr, 0L, QTh, QTm, sCN, KTh, KTm, sCN, VTh, sCN, nullptr, 0L);

  // V -> [c][n] plane; xc residual -> bf16 [c][n]  (coalesced transposes)
  transpose_vxc<<<dim3(50, 16, 8), 256, 0, stream>>>(
      VTh, xcTh, xcTm, Vh, xc_cn);

  // S = scale * QT . KT^T : [1600][1600] fp32
  mfma_gemm<2, 3><<<dim3(13 * 13 * 8), 256, 0, stream>>>(
      QTh, QTm, KTh, KTm, 13, 13, 1600, 1600, 512, 512, 512, sCN, sCN, nullptr, scale,
      S, sNN, nullptr, nullptr, 0L, nullptr, nullptr, 0L, nullptr, 0L,
      nullptr, 0L);

  // softmax + rank mask; writes w bf16 h-plane in place over S
  rowproc<<<dim3(12800), 256, 0, stream>>>(S);

  // out = V . w^T + xc : [512][1600] fp32 -> d_out (1-plane, 1-product)
  mfma_gemm<3, 1><<<dim3(13 * 4 * 8), 256, 0, stream>>>(
      Vh, nullptr, (unsigned short*)S, nullptr,
      13, 4, 512, 1600, 1600, 1600, 3200, sCN, 2L * sNN, nullptr, 1.f,
      out, sCN, nullptr, nullptr, 0L, nullptr, nullptr, 0L, nullptr, 0L,
      xc_cn, sCN);
}

// Round 10
// 405.356 us; speedup vs baseline: 2.0678x; 1.0941x over previous
//
#include <hip/hip_runtime.h>
#include <math.h>

typedef short short8 __attribute__((ext_vector_type(8)));
typedef float f32x16 __attribute__((ext_vector_type(16)));

__device__ __forceinline__ unsigned short f2bf(float f) {
  unsigned u = __float_as_uint(f);
  unsigned r = u + 0x7fffu + ((u >> 16) & 1u);
  return (unsigned short)(r >> 16);
}
__device__ __forceinline__ float bf2f(unsigned short s) {
  return __uint_as_float(((unsigned)s) << 16);
}
__device__ __forceinline__ void gload_lds16(const void* g, void* l) {
  __builtin_amdgcn_global_load_lds(
      (const __attribute__((address_space(1))) unsigned int*)g,
      (__attribute__((address_space(3))) unsigned int*)l, 16, 0, 0);
}

#define TM 128
#define TN 128
#define GH 7  // y-tiles grouped per rasterization column (L2 locality)

// NT MFMA GEMM. NPROD=3: 2-plane split (v~=h+m), products hh+hm+mh.
// NPROD=1: single bf16 plane, 1 product (for OUT: no sign decisions downstream).
// A [M][K] (ld=ldA), B [N][K] (ld=ldB). TK=32, SINGLE-buffer LDS;
// cross-block overlap hides the vmcnt drain (4+ blocks/CU).
// 1D grid = GX*GY*GZ blocks (divisible by 8), XCD-chunked + grouped raster.
// MODE: 0=XC 1=QKV 2=S 3=OUT
template<int MODE, int NPROD>
__global__ __launch_bounds__(256, 4) void mfma_gemm(
    const unsigned short* __restrict__ A0, const unsigned short* __restrict__ A1,
    const unsigned short* __restrict__ B0, const unsigned short* __restrict__ B1,
    int GX, int GY,
    int M, int N, int K, int ldA, int ldB, long sA, long sB,
    const float* __restrict__ bias, float alpha,
    float* __restrict__ outF, long sOutF,
    unsigned short* __restrict__ P0, unsigned short* __restrict__ P1, long sP,
    unsigned short* __restrict__ R0, unsigned short* __restrict__ R1, long sR,
    unsigned short* __restrict__ V0, long sV,
    const unsigned short* __restrict__ xcn, long sXcn)
{
  constexpr int NPL = (NPROD == 3) ? 2 : 1;
  __shared__ __align__(16) unsigned short As[NPL][128 * 32];
  __shared__ __align__(16) unsigned short Bs[NPL][128 * 32];

  const int tid = threadIdx.x;

  // ---- XCD-chunked bijective remap (total % 8 == 0) + grouped raster decode
  const int total = GX * GY * ((int)gridDim.x / (GX * GY));
  const int q = total >> 3;
  const int wg = blockIdx.x;
  const int c = (wg & 7) * q + (wg >> 3);
  const int pb = GX * GY;
  const int bz = c / pb;
  int r = c - bz * pb;
  const int gy = r / (GH * GX);
  int rr = r - gy * (GH * GX);
  const int hh = min(GH, GY - gy * GH);
  const int xt = rr / hh;
  const int yt = gy * GH + (rr - xt * hh);

  const int m0 = yt * TM, n0 = xt * TN;
  const int lane = tid & 63, w = tid >> 6;
  const int wm = w >> 1, wn = w & 1;
  const int g = lane >> 5, lr = lane & 31;

  // staging: issue i covers rows i*64 + (tid>>2), 16B slot tid&3; source
  // pre-swizzled so LDS slot s of row r holds k-chunk s ^ ((r>>1)&3)
  const int str = tid >> 2, sts = tid & 3;
  long aoff[2], boff[2];
#pragma unroll
  for (int i = 0; i < 2; i++) {
    const int rw = i * 64 + str;
    const int swc = (sts ^ ((rw >> 1) & 3)) * 8;
    aoff[i] = (long)min(m0 + rw, M - 1) * ldA + swc;
    boff[i] = (long)min(n0 + rw, N - 1) * ldB + swc;
  }
  const unsigned short* Ap[2];
  const unsigned short* Bp[2];
  Ap[0] = A0 + bz * sA;
  Bp[0] = B0 + bz * sB;
  Ap[1] = (NPL == 2) ? A1 + bz * sA : Ap[0];
  Bp[1] = (NPL == 2) ? B1 + bz * sB : Bp[0];

  f32x16 acc[2][2];
#pragma unroll
  for (int i = 0; i < 2; i++)
#pragma unroll
    for (int j = 0; j < 2; j++)
#pragma unroll
      for (int e = 0; e < 16; e++) acc[i][j][e] = 0.f;

  const int NT = K >> 5;

  for (int kt = 0; kt < NT; kt++) {
    const long k0 = (long)kt << 5;
    if (kt) __syncthreads();  // previous compute done before overwrite
#pragma unroll
    for (int p = 0; p < NPL; p++)
#pragma unroll
      for (int i = 0; i < 2; i++) {
        gload_lds16(Ap[p] + aoff[i] + k0, (char*)&As[p][0] + i * 4096 + tid * 16);
        gload_lds16(Bp[p] + boff[i] + k0, (char*)&Bs[p][0] + i * 4096 + tid * 16);
      }
    __syncthreads();  // drain staging; other resident blocks compute meanwhile

#pragma unroll
    for (int kk = 0; kk < 2; kk++) {
      short8 af[2][NPL], bf[2][NPL];
#pragma unroll
      for (int i = 0; i < 2; i++) {
        const int rowa = wm * 64 + i * 32 + lr;
        const int sla = ((kk * 2 + g) ^ ((rowa >> 1) & 3)) * 8;
#pragma unroll
        for (int p = 0; p < NPL; p++)
          af[i][p] = *(const short8*)&As[p][rowa * 32 + sla];
        const int rowb = wn * 64 + i * 32 + lr;
        const int slb = ((kk * 2 + g) ^ ((rowb >> 1) & 3)) * 8;
#pragma unroll
        for (int p = 0; p < NPL; p++)
          bf[i][p] = *(const short8*)&Bs[p][rowb * 32 + slb];
      }
      __builtin_amdgcn_s_setprio(1);
#pragma unroll
      for (int i = 0; i < 2; i++)
#pragma unroll
        for (int j = 0; j < 2; j++) {
          acc[i][j] = __builtin_amdgcn_mfma_f32_32x32x16_bf16(af[i][0], bf[j][0], acc[i][j], 0, 0, 0);
          if (NPROD == 3) {
            acc[i][j] = __builtin_amdgcn_mfma_f32_32x32x16_bf16(af[i][0], bf[j][1], acc[i][j], 0, 0, 0);
            acc[i][j] = __builtin_amdgcn_mfma_f32_32x32x16_bf16(af[i][1], bf[j][0], acc[i][j], 0, 0, 0);
          }
        }
      __builtin_amdgcn_s_setprio(0);
    }
  }

  // epilogue: row = m0+wm*64+i*32 + rq*8 + g*4 + t ; col = n0+wn*64+j*32+lr
#pragma unroll
  for (int i = 0; i < 2; i++)
#pragma unroll
    for (int j = 0; j < 2; j++) {
      const int cb = n0 + wn * 64 + j * 32;
      const int col = cb + lr;
#pragma unroll
      for (int rq = 0; rq < 4; rq++)
#pragma unroll
        for (int t = 0; t < 4; t++) {
          const int reg = rq * 4 + t;
          const int row = m0 + wm * 64 + i * 32 + rq * 8 + g * 4 + t;
          float v = acc[i][j][reg];
          if (MODE == 0) {  // XC: relu, 2-plane xcT [n][c]
            if (row < M) {
              v += bias[col];
              v = fmaxf(v, 0.f);
              const unsigned short h = f2bf(v);
              const unsigned short m_ = f2bf(v - bf2f(h));
              const long o = bz * sP + (long)row * 512 + col;
              P0[o] = h; P1[o] = m_;
            }
          } else if (MODE == 1) {  // QKV: [n][c] coalesced; V single-plane
            if (row < M) {
              v += bias[col];
              const unsigned short h = f2bf(v);
              const int sc = col & 511;
              if (cb < 512) {
                const unsigned short m_ = f2bf(v - bf2f(h));
                const long o = bz * sP + (long)row * 512 + sc;
                P0[o] = h; P1[o] = m_;
              } else if (cb < 1024) {
                const unsigned short m_ = f2bf(v - bf2f(h));
                const long o = bz * sR + (long)row * 512 + sc;
                R0[o] = h; R1[o] = m_;
              } else {
                V0[bz * sV + (long)row * 512 + sc] = h;
              }
            }
          } else if (MODE == 2) {  // S
            if (row < M && col < N)
              outF[bz * sOutF + (long)row * 1600 + col] = v * alpha;
          } else {  // OUT: += residual (xc_cn bf16, coalesced)
            if (col < N) {
              v += bf2f(xcn[bz * sXcn + (long)row * 1600 + col]);
              outF[bz * sOutF + (long)row * 1600 + col] = v;
            }
          }
        }
    }
}

// x [B][C][N] f32 -> xT planes [B][N][C] bf16 h/m
__global__ __launch_bounds__(256) void transpose_split_x(
    const float* __restrict__ x, unsigned short* __restrict__ X0,
    unsigned short* __restrict__ X1)
{
  __shared__ float t[32][33];
  const int bz = blockIdx.z;
  const int n0 = blockIdx.x * 32, c0 = blockIdx.y * 32;
  const int tx = threadIdx.x & 31, ty = threadIdx.x >> 5;
  const float* xb = x + (long)bz * 512 * 1600;
#pragma unroll
  for (int k = 0; k < 4; k++)
    t[ty + k * 8][tx] = xb[(long)(c0 + ty + k * 8) * 1600 + n0 + tx];
  __syncthreads();
  const long ob = (long)bz * 1600 * 512;
#pragma unroll
  for (int k = 0; k < 4; k++) {
    const float v = t[tx][ty + k * 8];
    const unsigned short h = f2bf(v);
    const unsigned short m_ = f2bf(v - bf2f(h));
    const long o = ob + (long)(n0 + ty + k * 8) * 512 + c0 + tx;
    X0[o] = h; X1[o] = m_;
  }
}

// V h-plane [n][c] -> [c][n]; xcT planes -> xc_cn bf16 [c][n] (h+m summed)
__global__ __launch_bounds__(256) void transpose_vxc(
    const unsigned short* __restrict__ VTh,
    const unsigned short* __restrict__ xcTh, const unsigned short* __restrict__ xcTm,
    unsigned short* __restrict__ Vh, unsigned short* __restrict__ xccn)
{
  __shared__ unsigned short th[32][33], tc[32][33];
  const int bz = blockIdx.z;
  const int n0 = blockIdx.x * 32, c0 = blockIdx.y * 32;
  const int tx = threadIdx.x & 31, ty = threadIdx.x >> 5;
  const long ib = (long)bz * 819200L;
#pragma unroll
  for (int k = 0; k < 4; k++) {
    const int rr = ty + k * 8;
    const long o = ib + (long)(n0 + rr) * 512 + c0 + tx;
    th[rr][tx] = VTh[o];
    tc[rr][tx] = f2bf(bf2f(xcTh[o]) + bf2f(xcTm[o]));
  }
  __syncthreads();
#pragma unroll
  for (int k = 0; k < 4; k++) {
    const int rr = ty + k * 8;
    const long o = ib + (long)(c0 + rr) * 1600 + n0 + tx;
    Vh[o] = th[tx][rr];
    xccn[o] = tc[tx][rr];
  }
}

__global__ __launch_bounds__(256) void split2_mat(
    const float* __restrict__ W, unsigned short* __restrict__ H,
    unsigned short* __restrict__ Mp, int n)
{
  const int i = blockIdx.x * 256 + threadIdx.x;
  if (i < n) {
    const float v = W[i];
    const unsigned short h = f2bf(v);
    H[i] = h; Mp[i] = f2bf(v - bf2f(h));
  }
}

// batched: bz selects (A,B) pair; W' = A @ B, planes written at rowoff = bz*512
__global__ __launch_bounds__(256) void combine_gemm3(
    const float* __restrict__ Aq, const float* __restrict__ Bq,
    const float* __restrict__ Ak, const float* __restrict__ Bk,
    const float* __restrict__ Av, const float* __restrict__ Bv,
    unsigned short* __restrict__ H, unsigned short* __restrict__ Mp)
{
  __shared__ float As[16][68];
  __shared__ float Bs[16][68];
  const int tid = threadIdx.x;
  const int bz = blockIdx.z;
  const float* A = (bz == 0) ? Aq : (bz == 1) ? Ak : Av;
  const float* B = (bz == 0) ? Bq : (bz == 1) ? Bk : Bv;
  const int rowoff = bz * 512;
  const int m0 = blockIdx.y * 64, n0 = blockIdx.x * 64;
  const int tx = tid & 15, ty = tid >> 4;
  float acc[4][4];
#pragma unroll
  for (int i = 0; i < 4; i++)
#pragma unroll
    for (int j = 0; j < 4; j++) acc[i][j] = 0.f;
  for (int k0 = 0; k0 < 512; k0 += 16) {
    {
      const int cA = tid & 15, r0 = tid >> 4;
#pragma unroll
      for (int l = 0; l < 4; l++)
        As[cA][r0 + 16 * l] = A[(long)(m0 + r0 + 16 * l) * 512 + (k0 + cA)];
      const int c2 = tid & 63, r2 = tid >> 6;
#pragma unroll
      for (int l = 0; l < 4; l++)
        Bs[r2 + 4 * l][c2] = B[(long)(k0 + r2 + 4 * l) * 512 + (n0 + c2)];
    }
    __syncthreads();
#pragma unroll
    for (int kk = 0; kk < 16; kk++) {
      float a[4], b[4];
#pragma unroll
      for (int i = 0; i < 4; i++) a[i] = As[kk][ty * 4 + i];
#pragma unroll
      for (int j = 0; j < 4; j++) b[j] = Bs[kk][tx * 4 + j];
#pragma unroll
      for (int i = 0; i < 4; i++)
#pragma unroll
        for (int j = 0; j < 4; j++) acc[i][j] = fmaf(a[i], b[j], acc[i][j]);
    }
    __syncthreads();
  }
#pragma unroll
  for (int i = 0; i < 4; i++) {
    const int m = rowoff + m0 + ty * 4 + i;
#pragma unroll
    for (int j = 0; j < 4; j++) {
      const int n = n0 + tx * 4 + j;
      const float v = acc[i][j];
      const unsigned short h = f2bf(v);
      const long o = (long)m * 512 + n;
      H[o] = h; Mp[o] = f2bf(v - bf2f(h));
    }
  }
}

// batched: bz selects (W2,b1,b2); bout offset bz*512
__global__ __launch_bounds__(256) void bias_combine3(
    const float* __restrict__ W2q, const float* __restrict__ b1q, const float* __restrict__ b2q,
    const float* __restrict__ W2k, const float* __restrict__ b1k, const float* __restrict__ b2k,
    const float* __restrict__ W2v, const float* __restrict__ b1v, const float* __restrict__ b2v,
    float* __restrict__ bout)
{
  const int bz = blockIdx.z;
  const float* W2 = (bz == 0) ? W2q : (bz == 1) ? W2k : W2v;
  const float* b1 = (bz == 0) ? b1q : (bz == 1) ? b1k : b1v;
  const float* b2 = (bz == 0) ? b2q : (bz == 1) ? b2k : b2v;
  const int o = blockIdx.x * 256 + threadIdx.x;
  if (o < 512) {
    float acc = b2[o];
    for (int t = 0; t < 512; t++) acc = fmaf(W2[(long)o * 512 + t], b1[t], acc);
    bout[bz * 512 + o] = acc;
  }
}

#define NROW 1600
#define NB 1024

// softmax + rank mask; reads S row fp32, writes w = attn*mask as ONE bf16 plane
// in place (row n: bf16[0..1599] of the old fp32 row).
// v5: LINEAR bins over [0, rmax] (refine groups ~1 elem), no wmask array
// (negatives written in scatter pass, positives written by refine), 5 barriers,
// 17.8 KB LDS -> 8 blocks/CU. Ranking math exact (refine handles collisions).
__global__ __launch_bounds__(256) void rowproc(float* __restrict__ S)
{
  __shared__ float sm[NROW];
  __shared__ unsigned short gidx[NROW];
  __shared__ int hist[NB];
  __shared__ int Rb[NB];
  __shared__ float redf[8];
  __shared__ int wtot[4];

  const int tid = threadIdx.x;
  const int lane = tid & 63, wid = tid >> 6;
  float* srow = S + (long)blockIdx.x * NROW;

  // ---- load + per-wave max; zero hist
  float lmax = -3.4e38f;
  for (int i = tid; i < NROW; i += 256) {
    const float v = srow[i];
    sm[i] = v;
    lmax = fmaxf(lmax, v);
  }
#pragma unroll
  for (int j = 0; j < NB / 256; j++) hist[tid + 256 * j] = 0;
#pragma unroll
  for (int d = 32; d; d >>= 1) lmax = fmaxf(lmax, __shfl_xor(lmax, d, 64));
  if (lane == 0) redf[wid] = lmax;
  __syncthreads();  // B1
  const float rmax = fmaxf(fmaxf(redf[0], redf[1]), fmaxf(redf[2], redf[3]));
  // linear bucket scale: v in [0, rmax] -> [0, NB); monotone, exact via refine
  const float bsc = (rmax > 0.f) ? (float)NB * (1.f - 1e-6f) / rmax : 0.f;

  // ---- expsum + histogram of positives
  float lsum = 0.f;
  for (int i = tid; i < NROW; i += 256) {
    const float v = sm[i];
    lsum += __expf(v - rmax);
    if (v >= 0.f) {
      const int b = min(NB - 1, (int)(v * bsc));
      atomicAdd(&hist[b], 1);
    }
  }
#pragma unroll
  for (int d = 32; d; d >>= 1) lsum += __shfl_xor(lsum, d, 64);
  if (lane == 0) redf[4 + wid] = lsum;
  __syncthreads();  // B2 (hist also complete)
  const float Z = redf[4] + redf[5] + redf[6] + redf[7];
  const float invZ = 1.f / Z;

  // ---- suffix scan: thread owns bins 4t..4t+3 (ascending); rank base of bin b
  // = #elements in bins > b
  const int h0 = hist[4 * tid], h1 = hist[4 * tid + 1];
  const int h2 = hist[4 * tid + 2], h3 = hist[4 * tid + 3];
  const int loc = h0 + h1 + h2 + h3;
  int suf = loc;
#pragma unroll
  for (int d = 1; d < 64; d <<= 1) {
    const int o = __shfl_down(suf, d, 64);
    if (lane + d < 64) suf += o;
  }
  if (lane == 0) wtot[wid] = suf;
  __syncthreads();  // B3
  int above = 0;
#pragma unroll
  for (int w2 = 0; w2 < 4; w2++)
    if (w2 > wid) above += wtot[w2];
  const int P = wtot[0] + wtot[1] + wtot[2] + wtot[3];
  const int hiAll = (suf - loc) + above;
  Rb[4 * tid + 3] = hiAll;
  Rb[4 * tid + 2] = hiAll + h3;
  Rb[4 * tid + 1] = hiAll + h3 + h2;
  Rb[4 * tid + 0] = hiAll + h3 + h2 + h1;
  __syncthreads();  // B4

  // ---- scatter positives into bin groups; write negatives (mask=1) directly
  unsigned short* wrow = (unsigned short*)srow;
  for (int i = tid; i < NROW; i += 256) {
    const float v = sm[i];
    if (v >= 0.f) {
      const int b = min(NB - 1, (int)(v * bsc));
      gidx[atomicAdd(&Rb[b], 1)] = (unsigned short)i;
    } else {
      wrow[i] = f2bf(__expf(v - rmax) * invZ);
    }
  }
  __syncthreads();  // B5
  // now Rb[b] = group end; start = Rb[b]-hist[b] = rank base

  // ---- within-bucket exact stable descending rank; write positives
  for (int p = tid; p < P; p += 256) {
    const int ip = gidx[p];
    const float vp = sm[ip];
    const int b = min(NB - 1, (int)(vp * bsc));
    const int end = Rb[b];
    const int start = end - hist[b];
    int cnt = 0;
    for (int qq = start; qq < end; qq++) {
      const int iq = gidx[qq];
      const float vq = sm[iq];
      cnt += (int)((vq > vp) || ((vq == vp) && (iq < ip)));
    }
    const float r1 = (float)(start + cnt + 1);
    wrow[ip] = f2bf(__expf(vp - rmax) * invZ * (r1 * r1 * r1));
  }
}

extern "C" void kernel_launch(void* const* d_in, const int* in_sizes, int n_in,
                              void* d_out, int out_size, void* d_ws, size_t ws_size,
                              hipStream_t stream)
{
  const float scale = 0.04419417382415922f;  // 1/sqrt(512)
  const long sCN = 819200L;                  // 512*1600
  const long sNN = 2560000L;                 // 1600*1600
  const long ePlane = 8L * sCN;              // elems per bf16 plane (batched)

  const float* x   = (const float*)d_in[0];
  const float* Wc  = (const float*)d_in[1];
  const float* bc  = (const float*)d_in[2];
  const float* Wq1 = (const float*)d_in[3];
  const float* bq1 = (const float*)d_in[4];
  const float* Wq2 = (const float*)d_in[5];
  const float* bq2 = (const float*)d_in[6];
  const float* Wk1 = (const float*)d_in[7];
  const float* bk1 = (const float*)d_in[8];
  const float* Wk2 = (const float*)d_in[9];
  const float* bk2 = (const float*)d_in[10];
  const float* Wv1 = (const float*)d_in[11];
  const float* bv1 = (const float*)d_in[12];
  const float* Wv2 = (const float*)d_in[13];
  const float* bv2 = (const float*)d_in[14];
  float* out = (float*)d_out;

  char* p = (char*)d_ws;
  auto carve = [&](size_t bytes) { char* r = p; p += (bytes + 255) & ~255UL; return r; };

  float* S = (float*)carve(8L * sNN * 4);  // S fp32; hosts xT planes early, w plane late
  unsigned short* Xh = (unsigned short*)S;
  unsigned short* Xm = Xh + ePlane;
  unsigned short* xcTh = (unsigned short*)carve(ePlane * 2);
  unsigned short* xcTm = (unsigned short*)carve(ePlane * 2);
  unsigned short* QTh = (unsigned short*)carve(ePlane * 2);
  unsigned short* QTm = (unsigned short*)carve(ePlane * 2);
  unsigned short* KTh = (unsigned short*)carve(ePlane * 2);
  unsigned short* KTm = (unsigned short*)carve(ePlane * 2);
  unsigned short* VTh = (unsigned short*)carve(ePlane * 2);
  unsigned short* Vh = (unsigned short*)carve(ePlane * 2);
  unsigned short* xc_cn = (unsigned short*)carve(ePlane * 2);
  unsigned short* Wch = (unsigned short*)carve(512L * 512 * 2);
  unsigned short* Wcm = (unsigned short*)carve(512L * 512 * 2);
  unsigned short* Wh = (unsigned short*)carve(1536L * 512 * 2);
  unsigned short* Wm = (unsigned short*)carve(1536L * 512 * 2);
  float* bqkv = (float*)carve(1536L * 4);

  // prep: x transpose+split, Wc split, combined weights/biases (batched)
  transpose_split_x<<<dim3(50, 16, 8), 256, 0, stream>>>(x, Xh, Xm);
  split2_mat<<<dim3(1024), 256, 0, stream>>>(Wc, Wch, Wcm, 512 * 512);
  combine_gemm3<<<dim3(8, 8, 3), 256, 0, stream>>>(Wq2, Wq1, Wk2, Wk1, Wv2, Wv1, Wh, Wm);
  bias_combine3<<<dim3(2, 1, 3), 256, 0, stream>>>(Wq2, bq1, bq2, Wk2, bk1, bk2,
                                                   Wv2, bv1, bv2, bqkv);

  // xc = relu(xT . Wc^T + bc): [1600][512] -> xcT 2 planes
  mfma_gemm<0, 3><<<dim3(4 * 13 * 8), 256, 0, stream>>>(
      Xh, Xm, Wch, Wcm, 4, 13, 1600, 512, 512, 512, 512, sCN, 0L, bc, 1.f,
      nullptr, 0L, xcTh, xcTm, sCN, nullptr, nullptr, 0L, nullptr, 0L,
      nullptr, 0L);

  // fused QKV: [1600][1536]; Q,K 2-plane, V 1-plane, all [n][c]
  mfma_gemm<1, 3><<<dim3(12 * 13 * 8), 256, 0, stream>>>(
      xcTh, xcTm, Wh, Wm, 12, 13, 1600, 1536, 512, 512, 512, sCN, 0L, bqkv, 1.f,
      nullptr, 0L, QTh, QTm, sCN, KTh, KTm, sCN, VTh, sCN, nullptr, 0L);

  // V -> [c][n] plane; xc residual -> bf16 [c][n]  (coalesced transposes)
  transpose_vxc<<<dim3(50, 16, 8), 256, 0, stream>>>(
      VTh, xcTh, xcTm, Vh, xc_cn);

  // S = scale * QT . KT^T : [1600][1600] fp32
  mfma_gemm<2, 3><<<dim3(13 * 13 * 8), 256, 0, stream>>>(
      QTh, QTm, KTh, KTm, 13, 13, 1600, 1600, 512, 512, 512, sCN, sCN, nullptr, scale,
      S, sNN, nullptr, nullptr, 0L, nullptr, nullptr, 0L, nullptr, 0L,
      nullptr, 0L);

  // softmax + rank mask; writes w bf16 plane in place over S
  rowproc<<<dim3(12800), 256, 0, stream>>>(S);

  // out = V . w^T + xc : [512][1600] fp32 -> d_out (1-plane, 1-product)
  mfma_gemm<3, 1><<<dim3(13 * 4 * 8), 256, 0, stream>>>(
      Vh, nullptr, (unsigned short*)S, nullptr,
      13, 4, 512, 1600, 1600, 1600, 3200, sCN, 2L * sNN, nullptr, 1.f,
      out, sCN, nullptr, nullptr, 0L, nullptr, nullptr, 0L, nullptr, 0L,
      xc_cn, sCN);
}